// Round 1
// baseline (316.969 us; speedup 1.0000x reference)
//
#include <hip/hip_runtime.h>

// ---------------------------------------------------------------------------
// CrossGraphNodeAttention: out = softmax(mask(Q K^T / 16)) V per batch
//   Q = A@Wq^T+bq, K = B@Wk^T+bk, V = B@Wv^T+bv;  B=8, N=2048, H=256
// Strategy: bf16 MFMA 16x16x32 everywhere, f32 accumulation.
//   proj kernel:  Qs (bf16, pre-scaled by log2e/16), K (bf16), VT (bf16, transposed)
//   attn kernel:  swapped QK^T (S^T in regs) -> in-lane online softmax -> PV
// ---------------------------------------------------------------------------

typedef __attribute__((ext_vector_type(8))) __bf16 bf16x8;
typedef __attribute__((ext_vector_type(4))) __bf16 bf16x4;
typedef __attribute__((ext_vector_type(4))) float f32x4;

#if __has_builtin(__builtin_amdgcn_exp2f)
#define EXP2(x) __builtin_amdgcn_exp2f(x)
#else
#define EXP2(x) exp2f(x)
#endif

#define MFMA16(a, b, c) __builtin_amdgcn_mfma_f32_16x16x32_bf16((a), (b), (c), 0, 0, 0)

static __device__ __forceinline__ bf16x8 pack8(f32x4 a, f32x4 b) {
  bf16x8 r;
  r[0] = (__bf16)a[0]; r[1] = (__bf16)a[1]; r[2] = (__bf16)a[2]; r[3] = (__bf16)a[3];
  r[4] = (__bf16)b[0]; r[5] = (__bf16)b[1]; r[6] = (__bf16)b[2]; r[7] = (__bf16)b[3];
  return r;
}

// ---------------------------------------------------------------------------
// mask bias: mb[b][n] = mask ? 0 : -1e30  (added to log2-domain scores)
// ---------------------------------------------------------------------------
__global__ void mask_kernel(const int* __restrict__ mask, float* __restrict__ mb) {
  int i = blockIdx.x * 256 + threadIdx.x;
  if (i < 8 * 2048) mb[i] = (mask[i] != 0) ? 0.0f : -1.0e30f;
}

// ---------------------------------------------------------------------------
// Projection: 384 blocks; block = 4 warps x 32 rows = 128 rows of one proj.
//  proj 0: Qs[R][n] = (A@Wq^T + bq) * log2e/16   (bf16)
//  proj 1: Ko[R][n] = (B@Wk^T + bk)              (bf16)
//  proj 2: VT[b][h][n] = (B@Wv^T + bv)^T         (bf16) via mfma(W, X) swap
// W staged in LDS bf16 in two 64KB halves, k-chunk XOR swizzle (bank conflicts).
// ---------------------------------------------------------------------------
__global__ __launch_bounds__(256, 2) void proj_kernel(
    const float* __restrict__ A, const float* __restrict__ Bm,
    const float* __restrict__ Wq, const float* __restrict__ bq,
    const float* __restrict__ Wk, const float* __restrict__ bk,
    const float* __restrict__ Wv, const float* __restrict__ bv,
    __bf16* __restrict__ Qs, __bf16* __restrict__ Ko, __bf16* __restrict__ VT) {
  __shared__ __bf16 Wl[256 * 128];  // 64 KB: half of W (k-half), swizzled
  const int pid = blockIdx.x;
  const int proj = pid >> 7;        // 0:Q 1:K 2:V
  const int rb = (pid & 127) << 7;  // row base in flattened [16384]
  const float* __restrict__ X = (proj == 0) ? A : Bm;
  const float* __restrict__ W = (proj == 0) ? Wq : (proj == 1 ? Wk : Wv);
  const float* __restrict__ bias = (proj == 0) ? bq : (proj == 1 ? bk : bv);
  const int tid = threadIdx.x;
  const int w = tid >> 6, l = tid & 63, lo = l & 15, g = l >> 4;
  const int r0 = rb + w * 32;

  f32x4 acc[2][16];
#pragma unroll
  for (int i = 0; i < 2; ++i)
#pragma unroll
    for (int j = 0; j < 16; ++j) acc[i][j] = (f32x4){0.f, 0.f, 0.f, 0.f};

  for (int half = 0; half < 2; ++half) {
    if (half) __syncthreads();  // all warps done reading previous half
    for (int c = tid; c < 4096; c += 256) {
      int n = c >> 4;
      int k8 = (c & 15) << 3;
      const float* wp = &W[n * 256 + half * 128 + k8];
      f32x4 w0 = *(const f32x4*)wp;
      f32x4 w1 = *(const f32x4*)(wp + 4);
      int kx = k8 ^ ((n & 7) << 3);  // 8-elem-chunk XOR swizzle
      *(bf16x8*)&Wl[n * 128 + kx] = pack8(w0, w1);
    }
    __syncthreads();
#pragma unroll
    for (int ks2 = 0; ks2 < 4; ++ks2) {
      const int kg = half * 128 + ks2 * 32 + g * 8;
      bf16x8 xf[2];
#pragma unroll
      for (int rt = 0; rt < 2; ++rt) {
        const float* xp = &X[(r0 + rt * 16 + lo) * 256 + kg];
        xf[rt] = pack8(*(const f32x4*)xp, *(const f32x4*)(xp + 4));
      }
#pragma unroll
      for (int nt = 0; nt < 16; ++nt) {
        int n = nt * 16 + lo;
        int kchunk = (ks2 * 4 + g) ^ (n & 7);
        bf16x8 wf = *(const bf16x8*)&Wl[n * 128 + kchunk * 8];
        if (proj == 2) {  // V: D = W * X^T -> VT[h][row]
          acc[0][nt] = MFMA16(wf, xf[0], acc[0][nt]);
          acc[1][nt] = MFMA16(wf, xf[1], acc[1][nt]);
        } else {  // Q/K: D = X * W^T -> out[row][n]
          acc[0][nt] = MFMA16(xf[0], wf, acc[0][nt]);
          acc[1][nt] = MFMA16(xf[1], wf, acc[1][nt]);
        }
      }
    }
  }

  if (proj != 2) {
    const float cs = (proj == 0) ? 0.090168440f : 1.0f;  // log2(e)/16
    __bf16* __restrict__ O = (proj == 0) ? Qs : Ko;
#pragma unroll
    for (int rt = 0; rt < 2; ++rt)
#pragma unroll
      for (int nt = 0; nt < 16; ++nt) {
        int n = nt * 16 + lo;
        float bb = bias[n];
#pragma unroll
        for (int r = 0; r < 4; ++r) {
          int R = r0 + rt * 16 + g * 4 + r;  // C-layout row
          O[R * 256 + n] = (__bf16)((acc[rt][nt][r] + bb) * cs);
        }
      }
  } else {
    const int bidx = r0 >> 11;
    const int nb = r0 & 2047;
#pragma unroll
    for (int rt = 0; rt < 2; ++rt)
#pragma unroll
      for (int ht = 0; ht < 16; ++ht)
#pragma unroll
        for (int r = 0; r < 4; ++r) {
          int h = ht * 16 + g * 4 + r;       // C-layout row = h
          int nr = nb + rt * 16 + lo;        // C-layout col = n-row
          VT[(size_t)bidx * 256 * 2048 + h * 2048 + nr] =
              (__bf16)(acc[rt][ht][r] + bias[h]);
        }
  }
}

// ---------------------------------------------------------------------------
// Attention: 256 blocks (8 batches x 32 q-tiles of 64), 4 warps x 16 q-rows.
// Per warp: sweep 2048 kv in blocks of 64. Swapped QK^T: S^T[kv][q] so each
// lane owns q = lane&15 (4 lanes/q). Online softmax in-register (base-2),
// defer-max (THR=8). P goes C-layout -> LDS -> B-layout frags for PV.
// ---------------------------------------------------------------------------
__global__ __launch_bounds__(256, 2) void attn_kernel(
    const __bf16* __restrict__ Qs, const __bf16* __restrict__ Ko,
    const __bf16* __restrict__ VT, const float* __restrict__ mb,
    float* __restrict__ out) {
  __shared__ __bf16 Pl[4][16][72];  // per-warp P tile [q][kv 64 + pad 8]
  const int bid = blockIdx.x;
  const int swz = (bid & 7) * 32 + (bid >> 3);  // XCD swizzle: batch -> XCD
  const int b = swz >> 5;
  const int qt = swz & 31;
  const int tid = threadIdx.x;
  const int w = tid >> 6, l = tid & 63, lo = l & 15, g = l >> 4;
  const int q0 = qt * 64 + w * 16;
  const __bf16* __restrict__ Qb = Qs + ((size_t)b * 2048 + q0) * 256;
  const __bf16* __restrict__ Kb = Ko + (size_t)b * 2048 * 256;
  const __bf16* __restrict__ Vb = VT + (size_t)b * 256 * 2048;
  const float* __restrict__ mbb = mb + b * 2048;

  bf16x8 qf[8];  // whole Q row-tile in regs (B-operand frags)
#pragma unroll
  for (int hs = 0; hs < 8; ++hs)
    qf[hs] = *(const bf16x8*)&Qb[lo * 256 + hs * 32 + g * 8];

  f32x4 oacc[16];
#pragma unroll
  for (int i = 0; i < 16; ++i) oacc[i] = (f32x4){0.f, 0.f, 0.f, 0.f};
  float m = -3.0e28f, lsum = 0.f;

  for (int kvb = 0; kvb < 2048; kvb += 64) {
    f32x4 sacc[4];
#pragma unroll
    for (int t = 0; t < 4; ++t) sacc[t] = (f32x4){0.f, 0.f, 0.f, 0.f};
#pragma unroll
    for (int t = 0; t < 4; ++t) {
      const __bf16* Kr = &Kb[(kvb + t * 16 + lo) * 256 + g * 8];
#pragma unroll
      for (int hs = 0; hs < 8; ++hs) {
        bf16x8 kf = *(const bf16x8*)&Kr[hs * 32];
        sacc[t] = MFMA16(kf, qf[hs], sacc[t]);  // S^T[kv][q]
      }
    }
    // mask bias + tile max (rows of lane: kv = kvb + t*16 + g*4 + r)
    float tmax = -3.4e38f;
#pragma unroll
    for (int t = 0; t < 4; ++t) {
      f32x4 bias4 = *(const f32x4*)&mbb[kvb + t * 16 + g * 4];
#pragma unroll
      for (int r = 0; r < 4; ++r) {
        sacc[t][r] += bias4[r];
        tmax = fmaxf(tmax, sacc[t][r]);
      }
    }
    tmax = fmaxf(tmax, __shfl_xor(tmax, 16));
    tmax = fmaxf(tmax, __shfl_xor(tmax, 32));
    if (!__all(tmax <= m + 8.0f)) {  // defer-max rescale
      float mn = fmaxf(m, tmax);
      float f = EXP2(m - mn);
      lsum *= f;
#pragma unroll
      for (int i = 0; i < 16; ++i) {
        oacc[i][0] *= f; oacc[i][1] *= f; oacc[i][2] *= f; oacc[i][3] *= f;
      }
      m = mn;
    }
    // P = exp2(s - m), accumulate l, stash to LDS (C-layout -> row-major [q][kv])
#pragma unroll
    for (int t = 0; t < 4; ++t) {
      float p0 = EXP2(sacc[t][0] - m);
      float p1 = EXP2(sacc[t][1] - m);
      float p2 = EXP2(sacc[t][2] - m);
      float p3 = EXP2(sacc[t][3] - m);
      lsum += (p0 + p1) + (p2 + p3);
      bf16x4 pk;
      pk[0] = (__bf16)p0; pk[1] = (__bf16)p1; pk[2] = (__bf16)p2; pk[3] = (__bf16)p3;
      *(bf16x4*)&Pl[w][lo][t * 16 + g * 4] = pk;
    }
    // PV: B-frags from LDS (same-wave write->read, compiler inserts lgkmcnt)
    bf16x8 pf0 = *(const bf16x8*)&Pl[w][lo][g * 8];
    bf16x8 pf1 = *(const bf16x8*)&Pl[w][lo][32 + g * 8];
#pragma unroll
    for (int ht = 0; ht < 16; ++ht) {
      const __bf16* Vr = &Vb[(ht * 16 + lo) * 2048 + kvb + g * 8];
      bf16x8 vf0 = *(const bf16x8*)&Vr[0];
      bf16x8 vf1 = *(const bf16x8*)&Vr[32];
      oacc[ht] = MFMA16(vf0, pf0, oacc[ht]);  // O^T[h][q]
      oacc[ht] = MFMA16(vf1, pf1, oacc[ht]);
    }
  }
  // final: combine the 4 lanes sharing q, divide, store f32 (16B per ht)
  lsum += __shfl_xor(lsum, 16);
  lsum += __shfl_xor(lsum, 32);
  float inv = 1.0f / lsum;
  float* __restrict__ Ob = out + ((size_t)b * 2048 + q0) * 256;
#pragma unroll
  for (int ht = 0; ht < 16; ++ht) {
    f32x4 v = oacc[ht];
    v[0] *= inv; v[1] *= inv; v[2] *= inv; v[3] *= inv;
    *(f32x4*)&Ob[lo * 256 + ht * 16 + g * 4] = v;
  }
}

// ---------------------------------------------------------------------------
extern "C" void kernel_launch(void* const* d_in, const int* in_sizes, int n_in,
                              void* d_out, int out_size, void* d_ws, size_t ws_size,
                              hipStream_t stream) {
  const float* A = (const float*)d_in[0];
  const float* B = (const float*)d_in[1];
  const int* mask = (const int*)d_in[2];
  const float* Wq = (const float*)d_in[3];
  const float* bq = (const float*)d_in[4];
  const float* Wk = (const float*)d_in[5];
  const float* bk = (const float*)d_in[6];
  const float* Wv = (const float*)d_in[7];
  const float* bv = (const float*)d_in[8];

  char* ws = (char*)d_ws;
  __bf16* Qs = (__bf16*)(ws);                       // 8 MB
  __bf16* Ko = (__bf16*)(ws + (8u << 20));          // 8 MB
  __bf16* VT = (__bf16*)(ws + (16u << 20));         // 8 MB
  float* mb = (float*)(ws + (24u << 20));           // 64 KB

  mask_kernel<<<64, 256, 0, stream>>>(mask, mb);
  proj_kernel<<<384, 256, 0, stream>>>(A, B, Wq, bq, Wk, bk, Wv, bv, Qs, Ko, VT);
  attn_kernel<<<256, 256, 0, stream>>>(Qs, Ko, VT, mb, (float*)d_out);
}

// Round 3
// 312.112 us; speedup vs baseline: 1.0156x; 1.0156x over previous
//
#include <hip/hip_runtime.h>

// ---------------------------------------------------------------------------
// CrossGraphNodeAttention: out = softmax(mask(Q K^T / 16)) V per batch
//   Q = A@Wq^T+bq, K = B@Wk^T+bk, V = B@Wv^T+bv;  B=8, N=2048, H=256
// bf16 MFMA 16x16x32, f32 accum. Round 2 (resubmit after infra failure):
// KV-split (S=4) flash decomposition to fix 1-wave/SIMD latency-bound attn
// (occupancy 10.9% -> ~40%).
// ---------------------------------------------------------------------------

typedef __attribute__((ext_vector_type(8))) __bf16 bf16x8;
typedef __attribute__((ext_vector_type(4))) __bf16 bf16x4;
typedef __attribute__((ext_vector_type(4))) float f32x4;

#if __has_builtin(__builtin_amdgcn_exp2f)
#define EXP2(x) __builtin_amdgcn_exp2f(x)
#else
#define EXP2(x) exp2f(x)
#endif

#define MFMA16(a, b, c) __builtin_amdgcn_mfma_f32_16x16x32_bf16((a), (b), (c), 0, 0, 0)

static __device__ __forceinline__ bf16x8 pack8(f32x4 a, f32x4 b) {
  bf16x8 r;
  r[0] = (__bf16)a[0]; r[1] = (__bf16)a[1]; r[2] = (__bf16)a[2]; r[3] = (__bf16)a[3];
  r[4] = (__bf16)b[0]; r[5] = (__bf16)b[1]; r[6] = (__bf16)b[2]; r[7] = (__bf16)b[3];
  return r;
}

// ---------------------------------------------------------------------------
// mask bias: mb[b][n] = mask ? 0 : -1e30  (added to log2-domain scores)
// ---------------------------------------------------------------------------
__global__ void mask_kernel(const int* __restrict__ mask, float* __restrict__ mb) {
  int i = blockIdx.x * 256 + threadIdx.x;
  if (i < 8 * 2048) mb[i] = (mask[i] != 0) ? 0.0f : -1.0e30f;
}

// ---------------------------------------------------------------------------
// Projection: 384 blocks; block = 4 warps x 32 rows = 128 rows of one proj.
//  proj 0: Qs[R][n] = (A@Wq^T + bq) * log2e/16   (bf16)
//  proj 1: Ko[R][n] = (B@Wk^T + bk)              (bf16)
//  proj 2: VT[b][h][n] = (B@Wv^T + bv)^T         (bf16) via mfma(W, X) swap
// ---------------------------------------------------------------------------
__global__ __launch_bounds__(256, 2) void proj_kernel(
    const float* __restrict__ A, const float* __restrict__ Bm,
    const float* __restrict__ Wq, const float* __restrict__ bq,
    const float* __restrict__ Wk, const float* __restrict__ bk,
    const float* __restrict__ Wv, const float* __restrict__ bv,
    __bf16* __restrict__ Qs, __bf16* __restrict__ Ko, __bf16* __restrict__ VT) {
  __shared__ __bf16 Wl[256 * 128];  // 64 KB: half of W (k-half), swizzled
  const int pid = blockIdx.x;
  const int proj = pid >> 7;        // 0:Q 1:K 2:V
  const int rb = (pid & 127) << 7;  // row base in flattened [16384]
  const float* __restrict__ X = (proj == 0) ? A : Bm;
  const float* __restrict__ W = (proj == 0) ? Wq : (proj == 1 ? Wk : Wv);
  const float* __restrict__ bias = (proj == 0) ? bq : (proj == 1 ? bk : bv);
  const int tid = threadIdx.x;
  const int w = tid >> 6, l = tid & 63, lo = l & 15, g = l >> 4;
  const int r0 = rb + w * 32;

  f32x4 acc[2][16];
#pragma unroll
  for (int i = 0; i < 2; ++i)
#pragma unroll
    for (int j = 0; j < 16; ++j) acc[i][j] = (f32x4){0.f, 0.f, 0.f, 0.f};

  for (int half = 0; half < 2; ++half) {
    if (half) __syncthreads();  // all warps done reading previous half
    for (int c = tid; c < 4096; c += 256) {
      int n = c >> 4;
      int k8 = (c & 15) << 3;
      const float* wp = &W[n * 256 + half * 128 + k8];
      f32x4 w0 = *(const f32x4*)wp;
      f32x4 w1 = *(const f32x4*)(wp + 4);
      int kx = k8 ^ ((n & 7) << 3);  // 8-elem-chunk XOR swizzle
      *(bf16x8*)&Wl[n * 128 + kx] = pack8(w0, w1);
    }
    __syncthreads();
#pragma unroll
    for (int ks2 = 0; ks2 < 4; ++ks2) {
      const int kg = half * 128 + ks2 * 32 + g * 8;
      bf16x8 xf[2];
#pragma unroll
      for (int rt = 0; rt < 2; ++rt) {
        const float* xp = &X[(r0 + rt * 16 + lo) * 256 + kg];
        xf[rt] = pack8(*(const f32x4*)xp, *(const f32x4*)(xp + 4));
      }
#pragma unroll
      for (int nt = 0; nt < 16; ++nt) {
        int n = nt * 16 + lo;
        int kchunk = (ks2 * 4 + g) ^ (n & 7);
        bf16x8 wf = *(const bf16x8*)&Wl[n * 128 + kchunk * 8];
        if (proj == 2) {  // V: D = W * X^T -> VT[h][row]
          acc[0][nt] = MFMA16(wf, xf[0], acc[0][nt]);
          acc[1][nt] = MFMA16(wf, xf[1], acc[1][nt]);
        } else {  // Q/K: D = X * W^T -> out[row][n]
          acc[0][nt] = MFMA16(xf[0], wf, acc[0][nt]);
          acc[1][nt] = MFMA16(xf[1], wf, acc[1][nt]);
        }
      }
    }
  }

  if (proj != 2) {
    const float cs = (proj == 0) ? 0.090168440f : 1.0f;  // log2(e)/16
    __bf16* __restrict__ O = (proj == 0) ? Qs : Ko;
#pragma unroll
    for (int rt = 0; rt < 2; ++rt)
#pragma unroll
      for (int nt = 0; nt < 16; ++nt) {
        int n = nt * 16 + lo;
        float bb = bias[n];
#pragma unroll
        for (int r = 0; r < 4; ++r) {
          int R = r0 + rt * 16 + g * 4 + r;  // C-layout row
          O[R * 256 + n] = (__bf16)((acc[rt][nt][r] + bb) * cs);
        }
      }
  } else {
    const int bidx = r0 >> 11;
    const int nb = r0 & 2047;
#pragma unroll
    for (int rt = 0; rt < 2; ++rt)
#pragma unroll
      for (int ht = 0; ht < 16; ++ht)
#pragma unroll
        for (int r = 0; r < 4; ++r) {
          int h = ht * 16 + g * 4 + r;       // C-layout row = h
          int nr = nb + rt * 16 + lo;        // C-layout col = n-row
          VT[(size_t)bidx * 256 * 2048 + h * 2048 + nr] =
              (__bf16)(acc[rt][ht][r] + bias[h]);
        }
  }
}

// ---------------------------------------------------------------------------
// Attention (KV-split): grid = 8 b x 32 qt x S splits; 4 warps x 16 q-rows.
// Each block sweeps a kv chunk of 2048/S. Swapped QK^T: S^T[kv][q], in-lane
// online softmax (base-2), defer-max (THR=8), P via per-warp LDS relayout.
// nsplit>=1: write unnormalized Opart (f32) + m,l partials.
// nsplit==0: direct mode, single chunk = full 2048, normalize + write out.
// ---------------------------------------------------------------------------
__global__ __launch_bounds__(256, 4) void attn_kernel(
    const __bf16* __restrict__ Qs, const __bf16* __restrict__ Ko,
    const __bf16* __restrict__ VT, const float* __restrict__ mb,
    float* __restrict__ Opart, float* __restrict__ mpart,
    float* __restrict__ lpart, float* __restrict__ out,
    int chunk, int direct) {
  __shared__ __bf16 Pl[4][16][72];  // per-warp P tile [q][kv 64 + pad 8]
  const int bid = blockIdx.x;
  const int b = bid & 7;            // batch -> XCD pinning
  const int rest = bid >> 3;
  const int qt = rest & 31;
  const int s = rest >> 5;
  const int tid = threadIdx.x;
  const int w = tid >> 6, l = tid & 63, lo = l & 15, g = l >> 4;
  const int q0 = qt * 64 + w * 16;
  const __bf16* __restrict__ Qb = Qs + ((size_t)b * 2048 + q0) * 256;
  const __bf16* __restrict__ Kb = Ko + (size_t)b * 2048 * 256;
  const __bf16* __restrict__ Vb = VT + (size_t)b * 256 * 2048;
  const float* __restrict__ mbb = mb + b * 2048;

  bf16x8 qf[8];  // whole Q row-tile in regs (B-operand frags)
#pragma unroll
  for (int hs = 0; hs < 8; ++hs)
    qf[hs] = *(const bf16x8*)&Qb[lo * 256 + hs * 32 + g * 8];

  f32x4 oacc[16];
#pragma unroll
  for (int i = 0; i < 16; ++i) oacc[i] = (f32x4){0.f, 0.f, 0.f, 0.f};
  float m = -3.0e28f, lsum = 0.f;

  const int kv0 = s * chunk, kv1 = kv0 + chunk;
  for (int kvb = kv0; kvb < kv1; kvb += 64) {
    f32x4 sacc[4];
#pragma unroll
    for (int t = 0; t < 4; ++t) sacc[t] = (f32x4){0.f, 0.f, 0.f, 0.f};
#pragma unroll
    for (int t = 0; t < 4; ++t) {
      const __bf16* Kr = &Kb[(kvb + t * 16 + lo) * 256 + g * 8];
#pragma unroll
      for (int hs = 0; hs < 8; ++hs) {
        bf16x8 kf = *(const bf16x8*)&Kr[hs * 32];
        sacc[t] = MFMA16(kf, qf[hs], sacc[t]);  // S^T[kv][q]
      }
    }
    // mask bias + tile max (rows of lane: kv = kvb + t*16 + g*4 + r)
    float tmax = -3.4e38f;
#pragma unroll
    for (int t = 0; t < 4; ++t) {
      f32x4 bias4 = *(const f32x4*)&mbb[kvb + t * 16 + g * 4];
#pragma unroll
      for (int r = 0; r < 4; ++r) {
        sacc[t][r] += bias4[r];
        tmax = fmaxf(tmax, sacc[t][r]);
      }
    }
    tmax = fmaxf(tmax, __shfl_xor(tmax, 16));
    tmax = fmaxf(tmax, __shfl_xor(tmax, 32));
    if (!__all(tmax <= m + 8.0f)) {  // defer-max rescale
      float mn = fmaxf(m, tmax);
      float f = EXP2(m - mn);
      lsum *= f;
#pragma unroll
      for (int i = 0; i < 16; ++i) {
        oacc[i][0] *= f; oacc[i][1] *= f; oacc[i][2] *= f; oacc[i][3] *= f;
      }
      m = mn;
    }
    // P = exp2(s - m), accumulate l, stash to LDS (C-layout -> row-major [q][kv])
#pragma unroll
    for (int t = 0; t < 4; ++t) {
      float p0 = EXP2(sacc[t][0] - m);
      float p1 = EXP2(sacc[t][1] - m);
      float p2 = EXP2(sacc[t][2] - m);
      float p3 = EXP2(sacc[t][3] - m);
      lsum += (p0 + p1) + (p2 + p3);
      bf16x4 pk;
      pk[0] = (__bf16)p0; pk[1] = (__bf16)p1; pk[2] = (__bf16)p2; pk[3] = (__bf16)p3;
      *(bf16x4*)&Pl[w][lo][t * 16 + g * 4] = pk;
    }
    // PV: B-frags from LDS (same-wave write->read)
    bf16x8 pf0 = *(const bf16x8*)&Pl[w][lo][g * 8];
    bf16x8 pf1 = *(const bf16x8*)&Pl[w][lo][32 + g * 8];
#pragma unroll
    for (int ht = 0; ht < 16; ++ht) {
      const __bf16* Vr = &Vb[(ht * 16 + lo) * 2048 + kvb + g * 8];
      bf16x8 vf0 = *(const bf16x8*)&Vr[0];
      bf16x8 vf1 = *(const bf16x8*)&Vr[32];
      oacc[ht] = MFMA16(vf0, pf0, oacc[ht]);  // O^T[h][q]
      oacc[ht] = MFMA16(vf1, pf1, oacc[ht]);
    }
  }
  // lane-combine l across the 4 lanes sharing q
  lsum += __shfl_xor(lsum, 16);
  lsum += __shfl_xor(lsum, 32);

  if (direct) {
    float inv = 1.0f / lsum;
    float* __restrict__ Ob = out + ((size_t)b * 2048 + q0) * 256;
#pragma unroll
    for (int ht = 0; ht < 16; ++ht) {
      f32x4 v = oacc[ht];
      v[0] *= inv; v[1] *= inv; v[2] *= inv; v[3] *= inv;
      *(f32x4*)&Ob[lo * 256 + ht * 16 + g * 4] = v;
    }
  } else {
    const size_t rowbase = (size_t)(s * 8 + b) * 2048 + q0;
    float* __restrict__ Ob = Opart + rowbase * 256;
#pragma unroll
    for (int ht = 0; ht < 16; ++ht)
      *(f32x4*)&Ob[lo * 256 + ht * 16 + g * 4] = oacc[ht];
    if (l < 16) {
      mpart[rowbase + lo] = m;
      lpart[rowbase + lo] = lsum;
    }
  }
}

// ---------------------------------------------------------------------------
// Combine: out[row][h] = sum_s 2^(m_s-M) O_s[row][h] / sum_s 2^(m_s-M) l_s
// 1M threads, 16B per thread, fully coalesced. Partials are L3-resident.
// ---------------------------------------------------------------------------
__global__ __launch_bounds__(256) void combine_kernel(
    const float* __restrict__ Opart, const float* __restrict__ mpart,
    const float* __restrict__ lpart, float* __restrict__ out, int nsplit) {
  int t = blockIdx.x * 256 + threadIdx.x;
  int row = t >> 6;
  int h4 = (t & 63) << 2;
  float M = -3.4e38f;
  for (int s = 0; s < nsplit; ++s) M = fmaxf(M, mpart[s * 16384 + row]);
  f32x4 acc = (f32x4){0.f, 0.f, 0.f, 0.f};
  float denom = 0.f;
  for (int s = 0; s < nsplit; ++s) {
    float wgt = EXP2(mpart[s * 16384 + row] - M);
    denom += wgt * lpart[s * 16384 + row];
    f32x4 o = *(const f32x4*)&Opart[((size_t)s * 16384 + row) * 256 + h4];
    acc[0] += wgt * o[0]; acc[1] += wgt * o[1];
    acc[2] += wgt * o[2]; acc[3] += wgt * o[3];
  }
  float inv = 1.0f / denom;
  f32x4 r;
  r[0] = acc[0] * inv; r[1] = acc[1] * inv;
  r[2] = acc[2] * inv; r[3] = acc[3] * inv;
  *(f32x4*)&out[(size_t)row * 256 + h4] = r;
}

// ---------------------------------------------------------------------------
extern "C" void kernel_launch(void* const* d_in, const int* in_sizes, int n_in,
                              void* d_out, int out_size, void* d_ws, size_t ws_size,
                              hipStream_t stream) {
  const float* A = (const float*)d_in[0];
  const float* B = (const float*)d_in[1];
  const int* mask = (const int*)d_in[2];
  const float* Wq = (const float*)d_in[3];
  const float* bq = (const float*)d_in[4];
  const float* Wk = (const float*)d_in[5];
  const float* bk = (const float*)d_in[6];
  const float* Wv = (const float*)d_in[7];
  const float* bv = (const float*)d_in[8];

  char* ws = (char*)d_ws;
  __bf16* Qs = (__bf16*)(ws);                         // 8 MB
  __bf16* Ko = (__bf16*)(ws + (8ull << 20));          // 8 MB
  __bf16* VT = (__bf16*)(ws + (16ull << 20));         // 8 MB
  float* mb = (float*)(ws + (24ull << 20));           // 64 KB
  float* mpart = (float*)(ws + (24ull << 20) + 0x10000);   // <=256 KB
  float* lpart = (float*)(ws + (24ull << 20) + 0x60000);   // <=256 KB
  float* Opart = (float*)(ws + (25ull << 20));             // S * 16 MB

  const size_t base = 25ull << 20;
  const size_t part = 16ull << 20;
  int S;
  if (ws_size >= base + 4 * part) S = 4;
  else if (ws_size >= base + 2 * part) S = 2;
  else if (ws_size >= base + 1 * part) S = 1;
  else S = 0;  // direct mode (no split)

  mask_kernel<<<64, 256, 0, stream>>>(mask, mb);
  proj_kernel<<<384, 256, 0, stream>>>(A, B, Wq, bq, Wk, bk, Wv, bv, Qs, Ko, VT);
  if (S == 0) {
    attn_kernel<<<256, 256, 0, stream>>>(Qs, Ko, VT, mb, nullptr, nullptr,
                                         nullptr, (float*)d_out, 2048, 1);
  } else {
    attn_kernel<<<256 * S, 256, 0, stream>>>(Qs, Ko, VT, mb, Opart, mpart,
                                             lpart, nullptr, 2048 / S, 0);
    combine_kernel<<<4096, 256, 0, stream>>>(Opart, mpart, lpart,
                                             (float*)d_out, S);
  }
}

// Round 4
// 258.187 us; speedup vs baseline: 1.2277x; 1.2089x over previous
//
#include <hip/hip_runtime.h>

// ---------------------------------------------------------------------------
// CrossGraphNodeAttention: out = softmax(mask(Q K^T / 16)) V per batch
//   Q = A@Wq^T+bq, K = B@Wk^T+bk, V = B@Wv^T+bv;  B=8, N=2048, H=256
// Round 4: fragment-major Q/K/V layouts. Round-3 post-mortem showed attn is
// L2-transaction-bound: fragment loads had 512B/4KB lane strides (64 lines
// per wave-load, 16B used per line). Projection now stores Q/K/V directly in
// MFMA-fragment order so every attn global load is base + lane*16B (fully
// coalesced, 8 full lines). KV-split S=2 for occupancy.
//   QF/KF[row16][hs(8)][g(4)][lo(16)][e(8)]  <-> row=grp*16+lo, h=hs*32+g*8+e
//   VF[kv64][ht(16)][c(8)][lo(16)][e(8)]     <-> h=ht*16+lo, kv=t64*64+c*8+e
// ---------------------------------------------------------------------------

typedef __attribute__((ext_vector_type(8))) __bf16 bf16x8;
typedef __attribute__((ext_vector_type(4))) __bf16 bf16x4;
typedef __attribute__((ext_vector_type(4))) float f32x4;

#if __has_builtin(__builtin_amdgcn_exp2f)
#define EXP2(x) __builtin_amdgcn_exp2f(x)
#else
#define EXP2(x) exp2f(x)
#endif

#define MFMA16(a, b, c) __builtin_amdgcn_mfma_f32_16x16x32_bf16((a), (b), (c), 0, 0, 0)

static __device__ __forceinline__ bf16x8 pack8(f32x4 a, f32x4 b) {
  bf16x8 r;
  r[0] = (__bf16)a[0]; r[1] = (__bf16)a[1]; r[2] = (__bf16)a[2]; r[3] = (__bf16)a[3];
  r[4] = (__bf16)b[0]; r[5] = (__bf16)b[1]; r[6] = (__bf16)b[2]; r[7] = (__bf16)b[3];
  return r;
}

// ---------------------------------------------------------------------------
__global__ void mask_kernel(const int* __restrict__ mask, float* __restrict__ mb) {
  int i = blockIdx.x * 256 + threadIdx.x;
  if (i < 8 * 2048) mb[i] = (mask[i] != 0) ? 0.0f : -1.0e30f;
}

// ---------------------------------------------------------------------------
// Projection: 384 blocks; block = 4 warps x 32 rows = 128 rows of one proj.
// Same MFMA core as r1-r3 (verified); stores now in fragment-major order.
// ---------------------------------------------------------------------------
__global__ __launch_bounds__(256, 2) void proj_kernel(
    const float* __restrict__ A, const float* __restrict__ Bm,
    const float* __restrict__ Wq, const float* __restrict__ bq,
    const float* __restrict__ Wk, const float* __restrict__ bk,
    const float* __restrict__ Wv, const float* __restrict__ bv,
    __bf16* __restrict__ QF, __bf16* __restrict__ KF, __bf16* __restrict__ VF) {
  __shared__ __bf16 Wl[256 * 128];  // 64 KB: half of W (k-half), swizzled
  const int pid = blockIdx.x;
  const int proj = pid >> 7;        // 0:Q 1:K 2:V
  const int rb = (pid & 127) << 7;  // row base in flattened [16384]
  const float* __restrict__ X = (proj == 0) ? A : Bm;
  const float* __restrict__ W = (proj == 0) ? Wq : (proj == 1 ? Wk : Wv);
  const float* __restrict__ bias = (proj == 0) ? bq : (proj == 1 ? bk : bv);
  const int tid = threadIdx.x;
  const int w = tid >> 6, l = tid & 63, lo = l & 15, g = l >> 4;
  const int r0 = rb + w * 32;

  f32x4 acc[2][16];
#pragma unroll
  for (int i = 0; i < 2; ++i)
#pragma unroll
    for (int j = 0; j < 16; ++j) acc[i][j] = (f32x4){0.f, 0.f, 0.f, 0.f};

  for (int half = 0; half < 2; ++half) {
    if (half) __syncthreads();  // all warps done reading previous half
    for (int c = tid; c < 4096; c += 256) {
      int n = c >> 4;
      int k8 = (c & 15) << 3;
      const float* wp = &W[n * 256 + half * 128 + k8];
      f32x4 w0 = *(const f32x4*)wp;
      f32x4 w1 = *(const f32x4*)(wp + 4);
      int kx = k8 ^ ((n & 7) << 3);  // 8-elem-chunk XOR swizzle
      *(bf16x8*)&Wl[n * 128 + kx] = pack8(w0, w1);
    }
    __syncthreads();
#pragma unroll
    for (int ks2 = 0; ks2 < 4; ++ks2) {
      const int kg = half * 128 + ks2 * 32 + g * 8;
      bf16x8 xf[2];
#pragma unroll
      for (int rt = 0; rt < 2; ++rt) {
        const float* xp = &X[(r0 + rt * 16 + lo) * 256 + kg];
        xf[rt] = pack8(*(const f32x4*)xp, *(const f32x4*)(xp + 4));
      }
#pragma unroll
      for (int nt = 0; nt < 16; ++nt) {
        int n = nt * 16 + lo;
        int kchunk = (ks2 * 4 + g) ^ (n & 7);
        bf16x8 wf = *(const bf16x8*)&Wl[n * 128 + kchunk * 8];
        if (proj == 2) {  // V: D = W * X^T -> VT[h][row]
          acc[0][nt] = MFMA16(wf, xf[0], acc[0][nt]);
          acc[1][nt] = MFMA16(wf, xf[1], acc[1][nt]);
        } else {  // Q/K: D = X * W^T -> out[row][n]
          acc[0][nt] = MFMA16(xf[0], wf, acc[0][nt]);
          acc[1][nt] = MFMA16(xf[1], wf, acc[1][nt]);
        }
      }
    }
  }

  if (proj != 2) {
    // fragment-major store: idx = (R>>4)*4096 + (h>>5)*512 + ((h>>3)&3)*128
    //                             + (R&15)*8 + (h&7)
    const float cs = (proj == 0) ? 0.090168440f : 1.0f;  // log2(e)/16
    __bf16* __restrict__ O = (proj == 0) ? QF : KF;
#pragma unroll
    for (int rt = 0; rt < 2; ++rt)
#pragma unroll
      for (int nt = 0; nt < 16; ++nt) {
        int h = nt * 16 + lo;
        float bb = bias[h];
        size_t hpart = (size_t)((h >> 5) << 9) + (((h >> 3) & 3) << 7) + (h & 7);
#pragma unroll
        for (int r = 0; r < 4; ++r) {
          int R = r0 + rt * 16 + g * 4 + r;  // C-layout row
          O[((size_t)(R >> 4) << 12) + hpart + ((R & 15) << 3)] =
              (__bf16)((acc[rt][nt][r] + bb) * cs);
        }
      }
  } else {
    // V fragment-major: idx = (n>>6)*16384 + (h>>4)*1024 + ((n>>3)&7)*128
    //                         + (h&15)*8 + (n&7)
    const int bidx = r0 >> 11;
    const int nb = r0 & 2047;
    __bf16* __restrict__ Vo = VF + (size_t)bidx * 524288;
#pragma unroll
    for (int rt = 0; rt < 2; ++rt)
#pragma unroll
      for (int ht = 0; ht < 16; ++ht)
#pragma unroll
        for (int r = 0; r < 4; ++r) {
          int h = ht * 16 + g * 4 + r;       // C-layout row = h
          int n = nb + rt * 16 + lo;         // C-layout col = kv
          Vo[((size_t)(n >> 6) << 14) + ((h >> 4) << 10) + (((n >> 3) & 7) << 7) +
             ((h & 15) << 3) + (n & 7)] = (__bf16)(acc[rt][ht][r] + bias[h]);
        }
  }
}

// ---------------------------------------------------------------------------
// Attention (KV-split): grid = 8 b x 32 qt x S; 4 warps x 16 q-rows.
// All global loads are now base + lane*16B (fragment-major layouts).
// ---------------------------------------------------------------------------
__global__ __launch_bounds__(256, 4) void attn_kernel(
    const __bf16* __restrict__ QF, const __bf16* __restrict__ KF,
    const __bf16* __restrict__ VF, const float* __restrict__ mb,
    float* __restrict__ Opart, float* __restrict__ mpart,
    float* __restrict__ lpart, float* __restrict__ out,
    int chunk, int direct) {
  __shared__ __bf16 Pl[4][16][72];  // per-warp P tile [q][kv 64 + pad 8]
  const int bid = blockIdx.x;
  const int b = bid & 7;            // batch -> XCD pinning
  const int rest = bid >> 3;
  const int qt = rest & 31;
  const int s = rest >> 5;
  const int tid = threadIdx.x;
  const int w = tid >> 6, l = tid & 63, lo = l & 15, g = l >> 4;
  const int q0 = qt * 64 + w * 16;
  const __bf16* __restrict__ Qb = QF + ((size_t)b * 2048 + q0) * 256;  // frag-major
  const __bf16* __restrict__ Kb = KF + (size_t)b * 2048 * 256;
  const __bf16* __restrict__ Vb = VF + (size_t)b * 524288;
  const float* __restrict__ mbb = mb + b * 2048;

  bf16x8 qf[8];  // whole Q row-tile in regs (B-operand frags)
#pragma unroll
  for (int hs = 0; hs < 8; ++hs)
    qf[hs] = *(const bf16x8*)&Qb[hs * 512 + l * 8];

  f32x4 oacc[16];
#pragma unroll
  for (int i = 0; i < 16; ++i) oacc[i] = (f32x4){0.f, 0.f, 0.f, 0.f};
  float m = -3.0e28f, lsum = 0.f;

  const int kv0 = s * chunk, kv1 = kv0 + chunk;
  for (int kvb = kv0; kvb < kv1; kvb += 64) {
    f32x4 sacc[4];
#pragma unroll
    for (int t = 0; t < 4; ++t) sacc[t] = (f32x4){0.f, 0.f, 0.f, 0.f};
#pragma unroll
    for (int t = 0; t < 4; ++t) {
      const __bf16* Kr = &Kb[(size_t)(kvb + t * 16) * 256 + l * 8];
#pragma unroll
      for (int hs = 0; hs < 8; ++hs) {
        bf16x8 kf = *(const bf16x8*)&Kr[hs * 512];
        sacc[t] = MFMA16(kf, qf[hs], sacc[t]);  // S^T[kv][q]
      }
    }
    // mask bias + tile max (rows of lane: kv = kvb + t*16 + g*4 + r)
    float tmax = -3.4e38f;
#pragma unroll
    for (int t = 0; t < 4; ++t) {
      f32x4 bias4 = *(const f32x4*)&mbb[kvb + t * 16 + g * 4];
#pragma unroll
      for (int r = 0; r < 4; ++r) {
        sacc[t][r] += bias4[r];
        tmax = fmaxf(tmax, sacc[t][r]);
      }
    }
    tmax = fmaxf(tmax, __shfl_xor(tmax, 16));
    tmax = fmaxf(tmax, __shfl_xor(tmax, 32));
    if (!__all(tmax <= m + 8.0f)) {  // defer-max rescale
      float mn = fmaxf(m, tmax);
      float f = EXP2(m - mn);
      lsum *= f;
#pragma unroll
      for (int i = 0; i < 16; ++i) {
        oacc[i][0] *= f; oacc[i][1] *= f; oacc[i][2] *= f; oacc[i][3] *= f;
      }
      m = mn;
    }
    // P = exp2(s - m), accumulate l, stash to LDS (C-layout -> row-major [q][kv])
#pragma unroll
    for (int t = 0; t < 4; ++t) {
      float p0 = EXP2(sacc[t][0] - m);
      float p1 = EXP2(sacc[t][1] - m);
      float p2 = EXP2(sacc[t][2] - m);
      float p3 = EXP2(sacc[t][3] - m);
      lsum += (p0 + p1) + (p2 + p3);
      bf16x4 pk;
      pk[0] = (__bf16)p0; pk[1] = (__bf16)p1; pk[2] = (__bf16)p2; pk[3] = (__bf16)p3;
      *(bf16x4*)&Pl[w][lo][t * 16 + g * 4] = pk;
    }
    // PV: B-frags from LDS (same-wave write->read)
    bf16x8 pf0 = *(const bf16x8*)&Pl[w][lo][g * 8];
    bf16x8 pf1 = *(const bf16x8*)&Pl[w][lo][32 + g * 8];
    const __bf16* Vt = &Vb[(size_t)(kvb >> 6) * 16384 + l * 8];
#pragma unroll
    for (int ht = 0; ht < 16; ++ht) {
      bf16x8 vf0 = *(const bf16x8*)&Vt[ht * 1024];
      bf16x8 vf1 = *(const bf16x8*)&Vt[ht * 1024 + 512];
      oacc[ht] = MFMA16(vf0, pf0, oacc[ht]);  // O^T[h][q]
      oacc[ht] = MFMA16(vf1, pf1, oacc[ht]);
    }
  }
  // lane-combine l across the 4 lanes sharing q
  lsum += __shfl_xor(lsum, 16);
  lsum += __shfl_xor(lsum, 32);

  if (direct) {
    float inv = 1.0f / lsum;
    float* __restrict__ Ob = out + ((size_t)b * 2048 + q0) * 256;
#pragma unroll
    for (int ht = 0; ht < 16; ++ht) {
      f32x4 v = oacc[ht];
      v[0] *= inv; v[1] *= inv; v[2] *= inv; v[3] *= inv;
      *(f32x4*)&Ob[lo * 256 + ht * 16 + g * 4] = v;
    }
  } else {
    const size_t rowbase = (size_t)(s * 8 + b) * 2048 + q0;
    float* __restrict__ Ob = Opart + rowbase * 256;
#pragma unroll
    for (int ht = 0; ht < 16; ++ht)
      *(f32x4*)&Ob[lo * 256 + ht * 16 + g * 4] = oacc[ht];
    if (l < 16) {
      mpart[rowbase + lo] = m;
      lpart[rowbase + lo] = lsum;
    }
  }
}

// ---------------------------------------------------------------------------
// Combine: out[row][h] = sum_s 2^(m_s-M) O_s[row][h] / sum_s 2^(m_s-M) l_s
// ---------------------------------------------------------------------------
__global__ __launch_bounds__(256) void combine_kernel(
    const float* __restrict__ Opart, const float* __restrict__ mpart,
    const float* __restrict__ lpart, float* __restrict__ out, int nsplit) {
  int t = blockIdx.x * 256 + threadIdx.x;
  int row = t >> 6;
  int h4 = (t & 63) << 2;
  float M = -3.4e38f;
  for (int s = 0; s < nsplit; ++s) M = fmaxf(M, mpart[s * 16384 + row]);
  f32x4 acc = (f32x4){0.f, 0.f, 0.f, 0.f};
  float denom = 0.f;
  for (int s = 0; s < nsplit; ++s) {
    float wgt = EXP2(mpart[s * 16384 + row] - M);
    denom += wgt * lpart[s * 16384 + row];
    f32x4 o = *(const f32x4*)&Opart[((size_t)s * 16384 + row) * 256 + h4];
    acc[0] += wgt * o[0]; acc[1] += wgt * o[1];
    acc[2] += wgt * o[2]; acc[3] += wgt * o[3];
  }
  float inv = 1.0f / denom;
  f32x4 r;
  r[0] = acc[0] * inv; r[1] = acc[1] * inv;
  r[2] = acc[2] * inv; r[3] = acc[3] * inv;
  *(f32x4*)&out[(size_t)row * 256 + h4] = r;
}

// ---------------------------------------------------------------------------
extern "C" void kernel_launch(void* const* d_in, const int* in_sizes, int n_in,
                              void* d_out, int out_size, void* d_ws, size_t ws_size,
                              hipStream_t stream) {
  const float* A = (const float*)d_in[0];
  const float* B = (const float*)d_in[1];
  const int* mask = (const int*)d_in[2];
  const float* Wq = (const float*)d_in[3];
  const float* bq = (const float*)d_in[4];
  const float* Wk = (const float*)d_in[5];
  const float* bk = (const float*)d_in[6];
  const float* Wv = (const float*)d_in[7];
  const float* bv = (const float*)d_in[8];

  char* ws = (char*)d_ws;
  __bf16* QF = (__bf16*)(ws);                         // 8 MB
  __bf16* KF = (__bf16*)(ws + (8ull << 20));          // 8 MB
  __bf16* VF = (__bf16*)(ws + (16ull << 20));         // 8 MB
  float* mb = (float*)(ws + (24ull << 20));           // 64 KB
  float* mpart = (float*)(ws + (24ull << 20) + 0x10000);   // <=256 KB
  float* lpart = (float*)(ws + (24ull << 20) + 0x60000);   // <=256 KB
  float* Opart = (float*)(ws + (25ull << 20));             // S * 16 MB

  const size_t base = 25ull << 20;
  const size_t part = 16ull << 20;
  int S;
  if (ws_size >= base + 2 * part) S = 2;
  else if (ws_size >= base + 1 * part) S = 1;
  else S = 0;  // direct mode (no split)

  mask_kernel<<<64, 256, 0, stream>>>(mask, mb);
  proj_kernel<<<384, 256, 0, stream>>>(A, B, Wq, bq, Wk, bk, Wv, bv, QF, KF, VF);
  if (S == 0) {
    attn_kernel<<<256, 256, 0, stream>>>(QF, KF, VF, mb, nullptr, nullptr,
                                         nullptr, (float*)d_out, 2048, 1);
  } else {
    attn_kernel<<<256 * S, 256, 0, stream>>>(QF, KF, VF, mb, Opart, mpart,
                                             lpart, nullptr, 2048 / S, 0);
    combine_kernel<<<4096, 256, 0, stream>>>(Opart, mpart, lpart,
                                             (float*)d_out, S);
  }
}

// Round 5
// 119.608 us; speedup vs baseline: 2.6501x; 2.1586x over previous
//
#include <hip/hip_runtime.h>

// ---------------------------------------------------------------------------
// CrossGraphNodeAttention: out = softmax(mask(Q K^T / 16)) V per batch
//   Q = A@Wq^T+bq, K = B@Wk^T+bk, V = B@Wv^T+bv;  B=8, N=2048, H=256
// Round 5: LDS-staged attn. Round-4 post-mortem: 4 warps/block re-read the
// same K/V tile from L2 (L1 thrashes) -> L2-throughput-bound at 6% MfmaUtil.
// Now: QBLK=128 (4 warps x 32q), K/V tiles staged to LDS once per block via
// global_load_lds (width 16, linear dest = fragment-major layout), double
// buffered, 1 barrier/iter. Grid 256 = 1 block/CU, batch->XCD pinned.
// ---------------------------------------------------------------------------

typedef __attribute__((ext_vector_type(8))) __bf16 bf16x8;
typedef __attribute__((ext_vector_type(4))) __bf16 bf16x4;
typedef __attribute__((ext_vector_type(4))) float f32x4;

#if __has_builtin(__builtin_amdgcn_exp2f)
#define EXP2(x) __builtin_amdgcn_exp2f(x)
#else
#define EXP2(x) exp2f(x)
#endif

#define MFMA16(a, b, c) __builtin_amdgcn_mfma_f32_16x16x32_bf16((a), (b), (c), 0, 0, 0)

typedef const __attribute__((address_space(1))) char gas_char;
typedef __attribute__((address_space(3))) char las_char;

// global -> LDS direct copy: 16B/lane, LDS dest = uniform base + lane*16.
static __device__ __forceinline__ void gload16(const void* g, void* l) {
  __builtin_amdgcn_global_load_lds((gas_char*)g, (las_char*)l, 16, 0, 0);
}

static __device__ __forceinline__ bf16x8 pack8(f32x4 a, f32x4 b) {
  bf16x8 r;
  r[0] = (__bf16)a[0]; r[1] = (__bf16)a[1]; r[2] = (__bf16)a[2]; r[3] = (__bf16)a[3];
  r[4] = (__bf16)b[0]; r[5] = (__bf16)b[1]; r[6] = (__bf16)b[2]; r[7] = (__bf16)b[3];
  return r;
}

// ---------------------------------------------------------------------------
__global__ void mask_kernel(const int* __restrict__ mask, float* __restrict__ mb) {
  int i = blockIdx.x * 256 + threadIdx.x;
  if (i < 8 * 2048) mb[i] = (mask[i] != 0) ? 0.0f : -1.0e30f;
}

// ---------------------------------------------------------------------------
// Projection: 384 blocks; block = 4 warps x 32 rows = 128 rows of one proj.
// Stores Q/K/V in MFMA-fragment-major order (verified r4).
// ---------------------------------------------------------------------------
__global__ __launch_bounds__(256, 2) void proj_kernel(
    const float* __restrict__ A, const float* __restrict__ Bm,
    const float* __restrict__ Wq, const float* __restrict__ bq,
    const float* __restrict__ Wk, const float* __restrict__ bk,
    const float* __restrict__ Wv, const float* __restrict__ bv,
    __bf16* __restrict__ QF, __bf16* __restrict__ KF, __bf16* __restrict__ VF) {
  __shared__ __bf16 Wl[256 * 128];  // 64 KB: half of W (k-half), swizzled
  const int pid = blockIdx.x;
  const int proj = pid >> 7;        // 0:Q 1:K 2:V
  const int rb = (pid & 127) << 7;  // row base in flattened [16384]
  const float* __restrict__ X = (proj == 0) ? A : Bm;
  const float* __restrict__ W = (proj == 0) ? Wq : (proj == 1 ? Wk : Wv);
  const float* __restrict__ bias = (proj == 0) ? bq : (proj == 1 ? bk : bv);
  const int tid = threadIdx.x;
  const int w = tid >> 6, l = tid & 63, lo = l & 15, g = l >> 4;
  const int r0 = rb + w * 32;

  f32x4 acc[2][16];
#pragma unroll
  for (int i = 0; i < 2; ++i)
#pragma unroll
    for (int j = 0; j < 16; ++j) acc[i][j] = (f32x4){0.f, 0.f, 0.f, 0.f};

  for (int half = 0; half < 2; ++half) {
    if (half) __syncthreads();  // all warps done reading previous half
    for (int c = tid; c < 4096; c += 256) {
      int n = c >> 4;
      int k8 = (c & 15) << 3;
      const float* wp = &W[n * 256 + half * 128 + k8];
      f32x4 w0 = *(const f32x4*)wp;
      f32x4 w1 = *(const f32x4*)(wp + 4);
      int kx = k8 ^ ((n & 7) << 3);  // 8-elem-chunk XOR swizzle
      *(bf16x8*)&Wl[n * 128 + kx] = pack8(w0, w1);
    }
    __syncthreads();
#pragma unroll
    for (int ks2 = 0; ks2 < 4; ++ks2) {
      const int kg = half * 128 + ks2 * 32 + g * 8;
      bf16x8 xf[2];
#pragma unroll
      for (int rt = 0; rt < 2; ++rt) {
        const float* xp = &X[(r0 + rt * 16 + lo) * 256 + kg];
        xf[rt] = pack8(*(const f32x4*)xp, *(const f32x4*)(xp + 4));
      }
#pragma unroll
      for (int nt = 0; nt < 16; ++nt) {
        int n = nt * 16 + lo;
        int kchunk = (ks2 * 4 + g) ^ (n & 7);
        bf16x8 wf = *(const bf16x8*)&Wl[n * 128 + kchunk * 8];
        if (proj == 2) {  // V: D = W * X^T -> VT[h][row]
          acc[0][nt] = MFMA16(wf, xf[0], acc[0][nt]);
          acc[1][nt] = MFMA16(wf, xf[1], acc[1][nt]);
        } else {  // Q/K: D = X * W^T -> out[row][n]
          acc[0][nt] = MFMA16(xf[0], wf, acc[0][nt]);
          acc[1][nt] = MFMA16(xf[1], wf, acc[1][nt]);
        }
      }
    }
  }

  if (proj != 2) {
    // fragment-major: idx = (R>>4)*4096 + (h>>5)*512 + ((h>>3)&3)*128
    //                       + (R&15)*8 + (h&7)
    const float cs = (proj == 0) ? 0.090168440f : 1.0f;  // log2(e)/16
    __bf16* __restrict__ O = (proj == 0) ? QF : KF;
#pragma unroll
    for (int rt = 0; rt < 2; ++rt)
#pragma unroll
      for (int nt = 0; nt < 16; ++nt) {
        int h = nt * 16 + lo;
        float bb = bias[h];
        size_t hpart = (size_t)((h >> 5) << 9) + (((h >> 3) & 3) << 7) + (h & 7);
#pragma unroll
        for (int r = 0; r < 4; ++r) {
          int R = r0 + rt * 16 + g * 4 + r;  // C-layout row
          O[((size_t)(R >> 4) << 12) + hpart + ((R & 15) << 3)] =
              (__bf16)((acc[rt][nt][r] + bb) * cs);
        }
      }
  } else {
    // V fragment-major: idx = (n>>6)*16384 + (h>>4)*1024 + ((n>>3)&7)*128
    //                         + (h&15)*8 + (n&7)
    const int bidx = r0 >> 11;
    const int nb = r0 & 2047;
    __bf16* __restrict__ Vo = VF + (size_t)bidx * 524288;
#pragma unroll
    for (int rt = 0; rt < 2; ++rt)
#pragma unroll
      for (int ht = 0; ht < 16; ++ht)
#pragma unroll
        for (int r = 0; r < 4; ++r) {
          int h = ht * 16 + g * 4 + r;       // C-layout row = h
          int n = nb + rt * 16 + lo;         // C-layout col = kv
          Vo[((size_t)(n >> 6) << 14) + ((h >> 4) << 10) + (((n >> 3) & 7) << 7) +
             ((h & 15) << 3) + (n & 7)] = (__bf16)(acc[rt][ht][r] + bias[h]);
        }
  }
}

// ---------------------------------------------------------------------------
// Attention: grid = 8 b x 16 qt x S; 4 warps x 32 q-rows (2 row-tiles).
// K/V tiles (32KB each) LDS-staged via global_load_lds, double-buffered.
// LDS: [K 2x32KB][V 2x32KB][P 4 warps x 2 tiles x 16 x 72] = 146KB dynamic.
// ---------------------------------------------------------------------------
__global__ __launch_bounds__(256, 1) void attn_kernel(
    const __bf16* __restrict__ QF, const __bf16* __restrict__ KF,
    const __bf16* __restrict__ VF, const float* __restrict__ mb,
    float* __restrict__ Opart, float* __restrict__ mpart,
    float* __restrict__ lpart, float* __restrict__ out,
    int chunk, int direct) {
  extern __shared__ char smem[];
  const int bid = blockIdx.x;
  const int b = bid & 7;            // batch -> XCD pinning
  const int rest = bid >> 3;
  const int qt = rest & 15;
  const int s = rest >> 4;
  const int tid = threadIdx.x;
  const int w = tid >> 6, l = tid & 63, lo = l & 15, g = l >> 4;
  const int q0 = qt * 128 + w * 32;
  const __bf16* __restrict__ Qb = QF + ((size_t)b * 2048 + q0) * 256;
  const __bf16* __restrict__ Kb = KF + (size_t)b * 2048 * 256;
  const __bf16* __restrict__ Vb = VF + (size_t)b * 524288;
  const float* __restrict__ mbb = mb + b * 2048;
  __bf16* Pw = (__bf16*)(smem + 131072) + w * 2304;  // 2 tiles x 16 x 72

  bf16x8 qf[2][8];  // 2 q-row-tiles, B-operand frags
#pragma unroll
  for (int u = 0; u < 2; ++u)
#pragma unroll
    for (int hs = 0; hs < 8; ++hs)
      qf[u][hs] = *(const bf16x8*)&Qb[u * 4096 + hs * 512 + l * 8];

  f32x4 oacc[2][16];
#pragma unroll
  for (int u = 0; u < 2; ++u)
#pragma unroll
    for (int i = 0; i < 16; ++i) oacc[u][i] = (f32x4){0.f, 0.f, 0.f, 0.f};
  float m[2] = {-3.0e28f, -3.0e28f}, lsum[2] = {0.f, 0.f};

  const int kv0 = s * chunk;
  const int niter = chunk >> 6;

  // prologue: stage tile 0 into buf 0
  {
    const __bf16* gk = Kb + (size_t)kv0 * 256 + w * 4096 + l * 8;
    const __bf16* gv = Vb + ((size_t)(kv0 >> 6) << 14) + w * 4096 + l * 8;
    char* lk = smem + w * 8192;
    char* lv = smem + 65536 + w * 8192;
#pragma unroll
    for (int j = 0; j < 8; ++j) {
      gload16(gk + j * 512, lk + j * 1024);
      gload16(gv + j * 512, lv + j * 1024);
    }
  }
  __syncthreads();  // drains vmcnt -> tile 0 visible

  for (int it = 0; it < niter; ++it) {
    const int kvb = kv0 + (it << 6);
    const int cur = it & 1;
    // prefetch next tile into the other buffer (lands during compute)
    if (it + 1 < niter) {
      const int nxt = cur ^ 1;
      const __bf16* gk = Kb + (size_t)(kvb + 64) * 256 + w * 4096 + l * 8;
      const __bf16* gv = Vb + ((size_t)((kvb >> 6) + 1) << 14) + w * 4096 + l * 8;
      char* lk = smem + nxt * 32768 + w * 8192;
      char* lv = smem + 65536 + nxt * 32768 + w * 8192;
#pragma unroll
      for (int j = 0; j < 8; ++j) {
        gload16(gk + j * 512, lk + j * 1024);
        gload16(gv + j * 512, lv + j * 1024);
      }
    }
    const char* kbase = smem + cur * 32768;
    const char* vbase = smem + 65536 + cur * 32768;

    // QK^T: each K frag feeds both q-tiles
    f32x4 sacc[2][4];
#pragma unroll
    for (int u = 0; u < 2; ++u)
#pragma unroll
      for (int t = 0; t < 4; ++t) sacc[u][t] = (f32x4){0.f, 0.f, 0.f, 0.f};
#pragma unroll
    for (int t = 0; t < 4; ++t)
#pragma unroll
      for (int hs = 0; hs < 8; ++hs) {
        bf16x8 kf = *(const bf16x8*)(kbase + t * 8192 + hs * 1024 + l * 16);
        sacc[0][t] = MFMA16(kf, qf[0][hs], sacc[0][t]);
        sacc[1][t] = MFMA16(kf, qf[1][hs], sacc[1][t]);
      }

    // mask bias (shared across q-tiles) + per-tile online softmax
    f32x4 bias4[4];
#pragma unroll
    for (int t = 0; t < 4; ++t)
      bias4[t] = *(const f32x4*)&mbb[kvb + t * 16 + g * 4];
#pragma unroll
    for (int u = 0; u < 2; ++u) {
      float tmax = -3.4e38f;
#pragma unroll
      for (int t = 0; t < 4; ++t)
#pragma unroll
        for (int r = 0; r < 4; ++r) {
          sacc[u][t][r] += bias4[t][r];
          tmax = fmaxf(tmax, sacc[u][t][r]);
        }
      tmax = fmaxf(tmax, __shfl_xor(tmax, 16));
      tmax = fmaxf(tmax, __shfl_xor(tmax, 32));
      if (!__all(tmax <= m[u] + 8.0f)) {  // defer-max rescale
        float mn = fmaxf(m[u], tmax);
        float f = EXP2(m[u] - mn);
        lsum[u] *= f;
#pragma unroll
        for (int i = 0; i < 16; ++i) {
          oacc[u][i][0] *= f; oacc[u][i][1] *= f;
          oacc[u][i][2] *= f; oacc[u][i][3] *= f;
        }
        m[u] = mn;
      }
#pragma unroll
      for (int t = 0; t < 4; ++t) {
        float p0 = EXP2(sacc[u][t][0] - m[u]);
        float p1 = EXP2(sacc[u][t][1] - m[u]);
        float p2 = EXP2(sacc[u][t][2] - m[u]);
        float p3 = EXP2(sacc[u][t][3] - m[u]);
        lsum[u] += (p0 + p1) + (p2 + p3);
        bf16x4 pk;
        pk[0] = (__bf16)p0; pk[1] = (__bf16)p1;
        pk[2] = (__bf16)p2; pk[3] = (__bf16)p3;
        *(bf16x4*)&Pw[u * 1152 + lo * 72 + t * 16 + g * 4] = pk;
      }
    }
    // P frags (same-wave LDS write->read)
    bf16x8 pf[2][2];
#pragma unroll
    for (int u = 0; u < 2; ++u) {
      pf[u][0] = *(const bf16x8*)&Pw[u * 1152 + lo * 72 + g * 8];
      pf[u][1] = *(const bf16x8*)&Pw[u * 1152 + lo * 72 + 32 + g * 8];
    }
    // PV: each V frag feeds both q-tiles
#pragma unroll
    for (int ht = 0; ht < 16; ++ht) {
      bf16x8 vf0 = *(const bf16x8*)(vbase + ht * 2048 + l * 16);
      bf16x8 vf1 = *(const bf16x8*)(vbase + ht * 2048 + 1024 + l * 16);
      oacc[0][ht] = MFMA16(vf0, pf[0][0], oacc[0][ht]);
      oacc[0][ht] = MFMA16(vf1, pf[0][1], oacc[0][ht]);
      oacc[1][ht] = MFMA16(vf0, pf[1][0], oacc[1][ht]);
      oacc[1][ht] = MFMA16(vf1, pf[1][1], oacc[1][ht]);
    }
    __syncthreads();  // drains vmcnt (prefetch landed); LDS reads done
  }

#pragma unroll
  for (int u = 0; u < 2; ++u) {
    float ls = lsum[u];
    ls += __shfl_xor(ls, 16);
    ls += __shfl_xor(ls, 32);
    const int q0u = q0 + u * 16;
    if (direct) {
      float inv = 1.0f / ls;
      float* __restrict__ Ob = out + ((size_t)b * 2048 + q0u) * 256;
#pragma unroll
      for (int ht = 0; ht < 16; ++ht) {
        f32x4 v = oacc[u][ht];
        v[0] *= inv; v[1] *= inv; v[2] *= inv; v[3] *= inv;
        *(f32x4*)&Ob[lo * 256 + ht * 16 + g * 4] = v;
      }
    } else {
      const size_t rowbase = (size_t)(s * 8 + b) * 2048 + q0u;
      float* __restrict__ Ob = Opart + rowbase * 256;
#pragma unroll
      for (int ht = 0; ht < 16; ++ht)
        *(f32x4*)&Ob[lo * 256 + ht * 16 + g * 4] = oacc[u][ht];
      if (l < 16) {
        mpart[rowbase + lo] = m[u];
        lpart[rowbase + lo] = ls;
      }
    }
  }
}

// ---------------------------------------------------------------------------
// Combine: out[row][h] = sum_s 2^(m_s-M) O_s[row][h] / sum_s 2^(m_s-M) l_s
// ---------------------------------------------------------------------------
__global__ __launch_bounds__(256) void combine_kernel(
    const float* __restrict__ Opart, const float* __restrict__ mpart,
    const float* __restrict__ lpart, float* __restrict__ out, int nsplit) {
  int t = blockIdx.x * 256 + threadIdx.x;
  int row = t >> 6;
  int h4 = (t & 63) << 2;
  float M = -3.4e38f;
  for (int s = 0; s < nsplit; ++s) M = fmaxf(M, mpart[s * 16384 + row]);
  f32x4 acc = (f32x4){0.f, 0.f, 0.f, 0.f};
  float denom = 0.f;
  for (int s = 0; s < nsplit; ++s) {
    float wgt = EXP2(mpart[s * 16384 + row] - M);
    denom += wgt * lpart[s * 16384 + row];
    f32x4 o = *(const f32x4*)&Opart[((size_t)s * 16384 + row) * 256 + h4];
    acc[0] += wgt * o[0]; acc[1] += wgt * o[1];
    acc[2] += wgt * o[2]; acc[3] += wgt * o[3];
  }
  float inv = 1.0f / denom;
  f32x4 r;
  r[0] = acc[0] * inv; r[1] = acc[1] * inv;
  r[2] = acc[2] * inv; r[3] = acc[3] * inv;
  *(f32x4*)&out[(size_t)row * 256 + h4] = r;
}

// ---------------------------------------------------------------------------
extern "C" void kernel_launch(void* const* d_in, const int* in_sizes, int n_in,
                              void* d_out, int out_size, void* d_ws, size_t ws_size,
                              hipStream_t stream) {
  const float* A = (const float*)d_in[0];
  const float* B = (const float*)d_in[1];
  const int* mask = (const int*)d_in[2];
  const float* Wq = (const float*)d_in[3];
  const float* bq = (const float*)d_in[4];
  const float* Wk = (const float*)d_in[5];
  const float* bk = (const float*)d_in[6];
  const float* Wv = (const float*)d_in[7];
  const float* bv = (const float*)d_in[8];

  char* ws = (char*)d_ws;
  __bf16* QF = (__bf16*)(ws);                         // 8 MB
  __bf16* KF = (__bf16*)(ws + (8ull << 20));          // 8 MB
  __bf16* VF = (__bf16*)(ws + (16ull << 20));         // 8 MB
  float* mb = (float*)(ws + (24ull << 20));           // 64 KB
  float* mpart = (float*)(ws + (24ull << 20) + 0x10000);   // <=256 KB
  float* lpart = (float*)(ws + (24ull << 20) + 0x60000);   // <=256 KB
  float* Opart = (float*)(ws + (25ull << 20));             // S * 16 MB

  const size_t base = 25ull << 20;
  const size_t part = 16ull << 20;
  int S;
  if (ws_size >= base + 2 * part) S = 2;
  else if (ws_size >= base + 1 * part) S = 1;
  else S = 0;  // direct mode (no split)

  const int SMEM = 131072 + 4 * 2 * 16 * 72 * 2;  // 149504 B
  (void)hipFuncSetAttribute((const void*)attn_kernel,
                            hipFuncAttributeMaxDynamicSharedMemorySize, SMEM);

  mask_kernel<<<64, 256, 0, stream>>>(mask, mb);
  proj_kernel<<<384, 256, 0, stream>>>(A, B, Wq, bq, Wk, bk, Wv, bv, QF, KF, VF);
  if (S == 0) {
    attn_kernel<<<128, 256, SMEM, stream>>>(QF, KF, VF, mb, nullptr, nullptr,
                                            nullptr, (float*)d_out, 2048, 1);
  } else {
    attn_kernel<<<128 * S, 256, SMEM, stream>>>(QF, KF, VF, mb, Opart, mpart,
                                                lpart, nullptr, 2048 / S, 0);
    combine_kernel<<<4096, 256, 0, stream>>>(Opart, mpart, lpart,
                                             (float*)d_out, S);
  }
}

// Round 6
// 109.802 us; speedup vs baseline: 2.8867x; 1.0893x over previous
//
#include <hip/hip_runtime.h>

// ---------------------------------------------------------------------------
// CrossGraphNodeAttention: out = softmax(mask(Q K^T / 16)) V per batch
//   Q = A@Wq^T+bq, K = B@Wk^T+bk, V = B@Wv^T+bv;  B=8, N=2048, H=256
// Round 6: occupancy fix. r5 was 1 wave/SIMD (146KB LDS) -> serial-chain
// latency exposed (MfmaUtil 17.5%). Now: one 8-warp block/CU (512 thr,
// QBLK=256), KVBLK=32 double-buffered (K/V 4x16KB), P stride-72; LDS=100KB
// -> 8 waves/CU = 2/SIMD. Staging shared by 8 warps (half the L2 fetch).
// Grid 8b x 8qt x S=4 = 256 blocks, batch->XCD pinned.
// ---------------------------------------------------------------------------

typedef __attribute__((ext_vector_type(8))) __bf16 bf16x8;
typedef __attribute__((ext_vector_type(4))) __bf16 bf16x4;
typedef __attribute__((ext_vector_type(4))) float f32x4;

#if __has_builtin(__builtin_amdgcn_exp2f)
#define EXP2(x) __builtin_amdgcn_exp2f(x)
#else
#define EXP2(x) exp2f(x)
#endif

#define MFMA16(a, b, c) __builtin_amdgcn_mfma_f32_16x16x32_bf16((a), (b), (c), 0, 0, 0)

typedef const __attribute__((address_space(1))) char gas_char;
typedef __attribute__((address_space(3))) char las_char;

// global -> LDS direct copy: 16B/lane, LDS dest = uniform base + lane*16.
static __device__ __forceinline__ void gload16(const void* g, void* l) {
  __builtin_amdgcn_global_load_lds((gas_char*)g, (las_char*)l, 16, 0, 0);
}

static __device__ __forceinline__ bf16x8 pack8(f32x4 a, f32x4 b) {
  bf16x8 r;
  r[0] = (__bf16)a[0]; r[1] = (__bf16)a[1]; r[2] = (__bf16)a[2]; r[3] = (__bf16)a[3];
  r[4] = (__bf16)b[0]; r[5] = (__bf16)b[1]; r[6] = (__bf16)b[2]; r[7] = (__bf16)b[3];
  return r;
}

// ---------------------------------------------------------------------------
__global__ void mask_kernel(const int* __restrict__ mask, float* __restrict__ mb) {
  int i = blockIdx.x * 256 + threadIdx.x;
  if (i < 8 * 2048) mb[i] = (mask[i] != 0) ? 0.0f : -1.0e30f;
}

// ---------------------------------------------------------------------------
// Projection: 384 blocks; block = 4 warps x 32 rows = 128 rows of one proj.
// Stores Q/K/V in MFMA-fragment-major order (verified r4/r5).
// ---------------------------------------------------------------------------
__global__ __launch_bounds__(256, 2) void proj_kernel(
    const float* __restrict__ A, const float* __restrict__ Bm,
    const float* __restrict__ Wq, const float* __restrict__ bq,
    const float* __restrict__ Wk, const float* __restrict__ bk,
    const float* __restrict__ Wv, const float* __restrict__ bv,
    __bf16* __restrict__ QF, __bf16* __restrict__ KF, __bf16* __restrict__ VF) {
  __shared__ __bf16 Wl[256 * 128];  // 64 KB: half of W (k-half), swizzled
  const int pid = blockIdx.x;
  const int proj = pid >> 7;        // 0:Q 1:K 2:V
  const int rb = (pid & 127) << 7;  // row base in flattened [16384]
  const float* __restrict__ X = (proj == 0) ? A : Bm;
  const float* __restrict__ W = (proj == 0) ? Wq : (proj == 1 ? Wk : Wv);
  const float* __restrict__ bias = (proj == 0) ? bq : (proj == 1 ? bk : bv);
  const int tid = threadIdx.x;
  const int w = tid >> 6, l = tid & 63, lo = l & 15, g = l >> 4;
  const int r0 = rb + w * 32;

  f32x4 acc[2][16];
#pragma unroll
  for (int i = 0; i < 2; ++i)
#pragma unroll
    for (int j = 0; j < 16; ++j) acc[i][j] = (f32x4){0.f, 0.f, 0.f, 0.f};

  for (int half = 0; half < 2; ++half) {
    if (half) __syncthreads();  // all warps done reading previous half
    for (int c = tid; c < 4096; c += 256) {
      int n = c >> 4;
      int k8 = (c & 15) << 3;
      const float* wp = &W[n * 256 + half * 128 + k8];
      f32x4 w0 = *(const f32x4*)wp;
      f32x4 w1 = *(const f32x4*)(wp + 4);
      int kx = k8 ^ ((n & 7) << 3);  // 8-elem-chunk XOR swizzle
      *(bf16x8*)&Wl[n * 128 + kx] = pack8(w0, w1);
    }
    __syncthreads();
#pragma unroll
    for (int ks2 = 0; ks2 < 4; ++ks2) {
      const int kg = half * 128 + ks2 * 32 + g * 8;
      bf16x8 xf[2];
#pragma unroll
      for (int rt = 0; rt < 2; ++rt) {
        const float* xp = &X[(r0 + rt * 16 + lo) * 256 + kg];
        xf[rt] = pack8(*(const f32x4*)xp, *(const f32x4*)(xp + 4));
      }
#pragma unroll
      for (int nt = 0; nt < 16; ++nt) {
        int n = nt * 16 + lo;
        int kchunk = (ks2 * 4 + g) ^ (n & 7);
        bf16x8 wf = *(const bf16x8*)&Wl[n * 128 + kchunk * 8];
        if (proj == 2) {  // V: D = W * X^T -> VT[h][row]
          acc[0][nt] = MFMA16(wf, xf[0], acc[0][nt]);
          acc[1][nt] = MFMA16(wf, xf[1], acc[1][nt]);
        } else {  // Q/K: D = X * W^T -> out[row][n]
          acc[0][nt] = MFMA16(xf[0], wf, acc[0][nt]);
          acc[1][nt] = MFMA16(xf[1], wf, acc[1][nt]);
        }
      }
    }
  }

  if (proj != 2) {
    // fragment-major: idx = (R>>4)*4096 + (h>>5)*512 + ((h>>3)&3)*128
    //                       + (R&15)*8 + (h&7)
    const float cs = (proj == 0) ? 0.090168440f : 1.0f;  // log2(e)/16
    __bf16* __restrict__ O = (proj == 0) ? QF : KF;
#pragma unroll
    for (int rt = 0; rt < 2; ++rt)
#pragma unroll
      for (int nt = 0; nt < 16; ++nt) {
        int h = nt * 16 + lo;
        float bb = bias[h];
        size_t hpart = (size_t)((h >> 5) << 9) + (((h >> 3) & 3) << 7) + (h & 7);
#pragma unroll
        for (int r = 0; r < 4; ++r) {
          int R = r0 + rt * 16 + g * 4 + r;  // C-layout row
          O[((size_t)(R >> 4) << 12) + hpart + ((R & 15) << 3)] =
              (__bf16)((acc[rt][nt][r] + bb) * cs);
        }
      }
  } else {
    // V fragment-major: idx = (n>>6)*16384 + (h>>4)*1024 + ((n>>3)&7)*128
    //                         + (h&15)*8 + (n&7)
    const int bidx = r0 >> 11;
    const int nb = r0 & 2047;
    __bf16* __restrict__ Vo = VF + (size_t)bidx * 524288;
#pragma unroll
    for (int rt = 0; rt < 2; ++rt)
#pragma unroll
      for (int ht = 0; ht < 16; ++ht)
#pragma unroll
        for (int r = 0; r < 4; ++r) {
          int h = ht * 16 + g * 4 + r;       // C-layout row = h
          int n = nb + rt * 16 + lo;         // C-layout col = kv
          Vo[((size_t)(n >> 6) << 14) + ((h >> 4) << 10) + (((n >> 3) & 7) << 7) +
             ((h & 15) << 3) + (n & 7)] = (__bf16)(acc[rt][ht][r] + bias[h]);
        }
  }
}

// ---------------------------------------------------------------------------
// Attention: grid = 8 b x 8 qt x S; 8 warps x 32 q-rows (QBLK=256).
// KVBLK=32: K/V tiles 16KB each, double-buffered (64KB) + P 8x4608B (36.9KB)
// = 100KB LDS -> one 8-warp block per CU = 2 waves/SIMD.
// ---------------------------------------------------------------------------
__global__ __launch_bounds__(512, 2) void attn_kernel(
    const __bf16* __restrict__ QF, const __bf16* __restrict__ KF,
    const __bf16* __restrict__ VF, const float* __restrict__ mb,
    float* __restrict__ Opart, float* __restrict__ mpart,
    float* __restrict__ lpart, float* __restrict__ out,
    int chunk, int direct) {
  extern __shared__ char smem[];  // [K 2x16K][V 2x16K][P 8x4608]
  const int bid = blockIdx.x;
  const int b = bid & 7;            // batch -> XCD pinning
  const int rest = bid >> 3;
  const int qt = rest & 7;
  const int s = rest >> 3;
  const int tid = threadIdx.x;
  const int w = tid >> 6, l = tid & 63, lo = l & 15, g = l >> 4;
  const int q0 = qt * 256 + w * 32;
  const __bf16* __restrict__ Qb = QF + ((size_t)b * 2048 + q0) * 256;
  const __bf16* __restrict__ Kb = KF + (size_t)b * 2048 * 256;
  const __bf16* __restrict__ Vb = VF + (size_t)b * 524288;
  const float* __restrict__ mbb = mb + b * 2048;
  __bf16* Pw = (__bf16*)(smem + 65536) + w * 2304;  // 2 tiles x 16 x 72

  bf16x8 qf[2][8];  // 2 q-row-tiles, B-operand frags
#pragma unroll
  for (int u = 0; u < 2; ++u)
#pragma unroll
    for (int hs = 0; hs < 8; ++hs)
      qf[u][hs] = *(const bf16x8*)&Qb[u * 4096 + hs * 512 + l * 8];

  f32x4 oacc[2][16];
#pragma unroll
  for (int u = 0; u < 2; ++u)
#pragma unroll
    for (int i = 0; i < 16; ++i) oacc[u][i] = (f32x4){0.f, 0.f, 0.f, 0.f};
  float m[2] = {-3.0e28f, -3.0e28f}, lsum[2] = {0.f, 0.f};

  const int kv0 = s * chunk;
  const int niter = chunk >> 5;

  // stage kv-32 tile `kvb` into buffer `buf`: warp w does 2 K + 2 V gloads.
  // K: 16KB contiguous at Kb + kvb*256 elems. V: 16 x 1KB chunks, one per
  // ht, at Vb + (kvb>>6)*16384 + ht*1024 + ((kvb>>5)&1)*512 elems.
  #define STAGE(kvb, buf)                                                     \
    {                                                                         \
      const char* gk = (const char*)(Kb + (size_t)(kvb) * 256) + w * 2048 +   \
                       l * 16;                                                \
      const char* gv = (const char*)(Vb + (((size_t)(kvb) >> 6) << 14) +      \
                                     (((kvb) >> 5) & 1) * 512) +              \
                       w * 4096 + l * 16;                                     \
      char* lk = smem + (buf)*16384 + w * 2048;                               \
      char* lv = smem + 32768 + (buf)*16384 + w * 2048;                       \
      gload16(gk, lk);                                                        \
      gload16(gk + 1024, lk + 1024);                                          \
      gload16(gv, lv);                                                        \
      gload16(gv + 2048, lv + 1024);                                          \
    }

  STAGE(kv0, 0);
  __syncthreads();  // drains vmcnt -> tile 0 visible

  for (int it = 0; it < niter; ++it) {
    const int kvb = kv0 + (it << 5);
    const int cur = it & 1;
    if (it + 1 < niter) STAGE(kvb + 32, cur ^ 1);  // prefetch into other buf
    const char* kbase = smem + cur * 16384;
    const char* vbase = smem + 32768 + cur * 16384;

    // QK^T: each K frag feeds both q-tiles
    f32x4 sacc[2][2];
#pragma unroll
    for (int u = 0; u < 2; ++u)
#pragma unroll
      for (int t = 0; t < 2; ++t) sacc[u][t] = (f32x4){0.f, 0.f, 0.f, 0.f};
#pragma unroll
    for (int t = 0; t < 2; ++t)
#pragma unroll
      for (int hs = 0; hs < 8; ++hs) {
        bf16x8 kf = *(const bf16x8*)(kbase + t * 8192 + hs * 1024 + l * 16);
        sacc[0][t] = MFMA16(kf, qf[0][hs], sacc[0][t]);
        sacc[1][t] = MFMA16(kf, qf[1][hs], sacc[1][t]);
      }

    // mask bias (shared across q-tiles) + per-tile online softmax
    f32x4 bias4[2];
#pragma unroll
    for (int t = 0; t < 2; ++t)
      bias4[t] = *(const f32x4*)&mbb[kvb + t * 16 + g * 4];
#pragma unroll
    for (int u = 0; u < 2; ++u) {
      float tmax = -3.4e38f;
#pragma unroll
      for (int t = 0; t < 2; ++t)
#pragma unroll
        for (int r = 0; r < 4; ++r) {
          sacc[u][t][r] += bias4[t][r];
          tmax = fmaxf(tmax, sacc[u][t][r]);
        }
      tmax = fmaxf(tmax, __shfl_xor(tmax, 16));
      tmax = fmaxf(tmax, __shfl_xor(tmax, 32));
      if (!__all(tmax <= m[u] + 8.0f)) {  // defer-max rescale
        float mn = fmaxf(m[u], tmax);
        float f = EXP2(m[u] - mn);
        lsum[u] *= f;
#pragma unroll
        for (int i = 0; i < 16; ++i) {
          oacc[u][i][0] *= f; oacc[u][i][1] *= f;
          oacc[u][i][2] *= f; oacc[u][i][3] *= f;
        }
        m[u] = mn;
      }
#pragma unroll
      for (int t = 0; t < 2; ++t) {
        float p0 = EXP2(sacc[u][t][0] - m[u]);
        float p1 = EXP2(sacc[u][t][1] - m[u]);
        float p2 = EXP2(sacc[u][t][2] - m[u]);
        float p3 = EXP2(sacc[u][t][3] - m[u]);
        lsum[u] += (p0 + p1) + (p2 + p3);
        bf16x4 pk;
        pk[0] = (__bf16)p0; pk[1] = (__bf16)p1;
        pk[2] = (__bf16)p2; pk[3] = (__bf16)p3;
        *(bf16x4*)&Pw[u * 1152 + lo * 72 + t * 16 + g * 4] = pk;
      }
    }
    // P frags (same-wave LDS write->read), one kv-32 frag per q-tile
    bf16x8 pf[2];
#pragma unroll
    for (int u = 0; u < 2; ++u)
      pf[u] = *(const bf16x8*)&Pw[u * 1152 + lo * 72 + g * 8];
    // PV: each V frag feeds both q-tiles
#pragma unroll
    for (int ht = 0; ht < 16; ++ht) {
      bf16x8 vf = *(const bf16x8*)(vbase + ht * 1024 + l * 16);
      oacc[0][ht] = MFMA16(vf, pf[0], oacc[0][ht]);
      oacc[1][ht] = MFMA16(vf, pf[1], oacc[1][ht]);
    }
    __syncthreads();  // drains vmcnt (prefetch landed); LDS reads done
  }

#pragma unroll
  for (int u = 0; u < 2; ++u) {
    float ls = lsum[u];
    ls += __shfl_xor(ls, 16);
    ls += __shfl_xor(ls, 32);
    const int q0u = q0 + u * 16;
    if (direct) {
      float inv = 1.0f / ls;
      float* __restrict__ Ob = out + ((size_t)b * 2048 + q0u) * 256;
#pragma unroll
      for (int ht = 0; ht < 16; ++ht) {
        f32x4 v = oacc[u][ht];
        v[0] *= inv; v[1] *= inv; v[2] *= inv; v[3] *= inv;
        *(f32x4*)&Ob[lo * 256 + ht * 16 + g * 4] = v;
      }
    } else {
      const size_t rowbase = (size_t)(s * 8 + b) * 2048 + q0u;
      float* __restrict__ Ob = Opart + rowbase * 256;
#pragma unroll
      for (int ht = 0; ht < 16; ++ht)
        *(f32x4*)&Ob[lo * 256 + ht * 16 + g * 4] = oacc[u][ht];
      if (l < 16) {
        mpart[rowbase + lo] = m[u];
        lpart[rowbase + lo] = ls;
      }
    }
  }
}

// ---------------------------------------------------------------------------
// Combine: out[row][h] = sum_s 2^(m_s-M) O_s[row][h] / sum_s 2^(m_s-M) l_s
// ---------------------------------------------------------------------------
__global__ __launch_bounds__(256) void combine_kernel(
    const float* __restrict__ Opart, const float* __restrict__ mpart,
    const float* __restrict__ lpart, float* __restrict__ out, int nsplit) {
  int t = blockIdx.x * 256 + threadIdx.x;
  int row = t >> 6;
  int h4 = (t & 63) << 2;
  float M = -3.4e38f;
  for (int s = 0; s < nsplit; ++s) M = fmaxf(M, mpart[s * 16384 + row]);
  f32x4 acc = (f32x4){0.f, 0.f, 0.f, 0.f};
  float denom = 0.f;
  for (int s = 0; s < nsplit; ++s) {
    float wgt = EXP2(mpart[s * 16384 + row] - M);
    denom += wgt * lpart[s * 16384 + row];
    f32x4 o = *(const f32x4*)&Opart[((size_t)s * 16384 + row) * 256 + h4];
    acc[0] += wgt * o[0]; acc[1] += wgt * o[1];
    acc[2] += wgt * o[2]; acc[3] += wgt * o[3];
  }
  float inv = 1.0f / denom;
  f32x4 r;
  r[0] = acc[0] * inv; r[1] = acc[1] * inv;
  r[2] = acc[2] * inv; r[3] = acc[3] * inv;
  *(f32x4*)&out[(size_t)row * 256 + h4] = r;
}

// ---------------------------------------------------------------------------
extern "C" void kernel_launch(void* const* d_in, const int* in_sizes, int n_in,
                              void* d_out, int out_size, void* d_ws, size_t ws_size,
                              hipStream_t stream) {
  const float* A = (const float*)d_in[0];
  const float* B = (const float*)d_in[1];
  const int* mask = (const int*)d_in[2];
  const float* Wq = (const float*)d_in[3];
  const float* bq = (const float*)d_in[4];
  const float* Wk = (const float*)d_in[5];
  const float* bk = (const float*)d_in[6];
  const float* Wv = (const float*)d_in[7];
  const float* bv = (const float*)d_in[8];

  char* ws = (char*)d_ws;
  __bf16* QF = (__bf16*)(ws);                         // 8 MB
  __bf16* KF = (__bf16*)(ws + (8ull << 20));          // 8 MB
  __bf16* VF = (__bf16*)(ws + (16ull << 20));         // 8 MB
  float* mb = (float*)(ws + (24ull << 20));           // 64 KB
  float* mpart = (float*)(ws + (24ull << 20) + 0x10000);   // <=256 KB
  float* lpart = (float*)(ws + (24ull << 20) + 0x60000);   // <=256 KB
  float* Opart = (float*)(ws + (25ull << 20));             // S * 16 MB

  const size_t base = 25ull << 20;
  const size_t part = 16ull << 20;
  int S;
  if (ws_size >= base + 4 * part) S = 4;
  else if (ws_size >= base + 2 * part) S = 2;
  else if (ws_size >= base + 1 * part) S = 1;
  else S = 0;  // direct mode (no split)

  const int SMEM = 65536 + 8 * 2 * 16 * 72 * 2;  // 102400 B
  (void)hipFuncSetAttribute((const void*)attn_kernel,
                            hipFuncAttributeMaxDynamicSharedMemorySize, SMEM);

  mask_kernel<<<64, 256, 0, stream>>>(mask, mb);
  proj_kernel<<<384, 256, 0, stream>>>(A, B, Wq, bq, Wk, bk, Wv, bv, QF, KF, VF);
  if (S == 0) {
    attn_kernel<<<64, 512, SMEM, stream>>>(QF, KF, VF, mb, nullptr, nullptr,
                                           nullptr, (float*)d_out, 2048, 1);
  } else {
    attn_kernel<<<64 * S, 512, SMEM, stream>>>(QF, KF, VF, mb, Opart, mpart,
                                               lpart, nullptr, 2048 / S, 0);
    combine_kernel<<<4096, 256, 0, stream>>>(Opart, mpart, lpart,
                                             (float*)d_out, S);
  }
}

// Round 7
// 106.092 us; speedup vs baseline: 2.9877x; 1.0350x over previous
//
#include <hip/hip_runtime.h>

// ---------------------------------------------------------------------------
// CrossGraphNodeAttention: out = softmax(mask(Q K^T / 16)) V per batch
//   Q = A@Wq^T+bq, K = B@Wk^T+bk, V = B@Wv^T+bv;  B=8, N=2048, H=256
// Round 7: two independent 4-warp blocks per CU. r6 post-mortem: one 8-warp
// barrier-locked block/CU -> whole-CU stall at every barrier (m233's 2-phase
// overhead) + 1-block/CU dispatch imbalance. Now: QBLK=128, KVBLK=32,
// LDS 75.8KB (K/V dbuf 64K + P stride-40 10K) -> 2 blocks/CU, barrier-
// independent; grid 512 = 2/CU balanced. T5 setprio around MFMA clusters.
// ---------------------------------------------------------------------------

typedef __attribute__((ext_vector_type(8))) __bf16 bf16x8;
typedef __attribute__((ext_vector_type(4))) __bf16 bf16x4;
typedef __attribute__((ext_vector_type(4))) float f32x4;

#if __has_builtin(__builtin_amdgcn_exp2f)
#define EXP2(x) __builtin_amdgcn_exp2f(x)
#else
#define EXP2(x) exp2f(x)
#endif

#define MFMA16(a, b, c) __builtin_amdgcn_mfma_f32_16x16x32_bf16((a), (b), (c), 0, 0, 0)

typedef const __attribute__((address_space(1))) char gas_char;
typedef __attribute__((address_space(3))) char las_char;

// global -> LDS direct copy: 16B/lane, LDS dest = uniform base + lane*16.
static __device__ __forceinline__ void gload16(const void* g, void* l) {
  __builtin_amdgcn_global_load_lds((gas_char*)g, (las_char*)l, 16, 0, 0);
}

static __device__ __forceinline__ bf16x8 pack8(f32x4 a, f32x4 b) {
  bf16x8 r;
  r[0] = (__bf16)a[0]; r[1] = (__bf16)a[1]; r[2] = (__bf16)a[2]; r[3] = (__bf16)a[3];
  r[4] = (__bf16)b[0]; r[5] = (__bf16)b[1]; r[6] = (__bf16)b[2]; r[7] = (__bf16)b[3];
  return r;
}

// ---------------------------------------------------------------------------
__global__ void mask_kernel(const int* __restrict__ mask, float* __restrict__ mb) {
  int i = blockIdx.x * 256 + threadIdx.x;
  if (i < 8 * 2048) mb[i] = (mask[i] != 0) ? 0.0f : -1.0e30f;
}

// ---------------------------------------------------------------------------
// Projection: 384 blocks; block = 4 warps x 32 rows = 128 rows of one proj.
// Stores Q/K/V in MFMA-fragment-major order (verified r4-r6).
// ---------------------------------------------------------------------------
__global__ __launch_bounds__(256, 2) void proj_kernel(
    const float* __restrict__ A, const float* __restrict__ Bm,
    const float* __restrict__ Wq, const float* __restrict__ bq,
    const float* __restrict__ Wk, const float* __restrict__ bk,
    const float* __restrict__ Wv, const float* __restrict__ bv,
    __bf16* __restrict__ QF, __bf16* __restrict__ KF, __bf16* __restrict__ VF) {
  __shared__ __bf16 Wl[256 * 128];  // 64 KB: half of W (k-half), swizzled
  const int pid = blockIdx.x;
  const int proj = pid >> 7;        // 0:Q 1:K 2:V
  const int rb = (pid & 127) << 7;  // row base in flattened [16384]
  const float* __restrict__ X = (proj == 0) ? A : Bm;
  const float* __restrict__ W = (proj == 0) ? Wq : (proj == 1 ? Wk : Wv);
  const float* __restrict__ bias = (proj == 0) ? bq : (proj == 1 ? bk : bv);
  const int tid = threadIdx.x;
  const int w = tid >> 6, l = tid & 63, lo = l & 15, g = l >> 4;
  const int r0 = rb + w * 32;

  f32x4 acc[2][16];
#pragma unroll
  for (int i = 0; i < 2; ++i)
#pragma unroll
    for (int j = 0; j < 16; ++j) acc[i][j] = (f32x4){0.f, 0.f, 0.f, 0.f};

  for (int half = 0; half < 2; ++half) {
    if (half) __syncthreads();  // all warps done reading previous half
    for (int c = tid; c < 4096; c += 256) {
      int n = c >> 4;
      int k8 = (c & 15) << 3;
      const float* wp = &W[n * 256 + half * 128 + k8];
      f32x4 w0 = *(const f32x4*)wp;
      f32x4 w1 = *(const f32x4*)(wp + 4);
      int kx = k8 ^ ((n & 7) << 3);  // 8-elem-chunk XOR swizzle
      *(bf16x8*)&Wl[n * 128 + kx] = pack8(w0, w1);
    }
    __syncthreads();
#pragma unroll
    for (int ks2 = 0; ks2 < 4; ++ks2) {
      const int kg = half * 128 + ks2 * 32 + g * 8;
      bf16x8 xf[2];
#pragma unroll
      for (int rt = 0; rt < 2; ++rt) {
        const float* xp = &X[(r0 + rt * 16 + lo) * 256 + kg];
        xf[rt] = pack8(*(const f32x4*)xp, *(const f32x4*)(xp + 4));
      }
#pragma unroll
      for (int nt = 0; nt < 16; ++nt) {
        int n = nt * 16 + lo;
        int kchunk = (ks2 * 4 + g) ^ (n & 7);
        bf16x8 wf = *(const bf16x8*)&Wl[n * 128 + kchunk * 8];
        if (proj == 2) {  // V: D = W * X^T -> VT[h][row]
          acc[0][nt] = MFMA16(wf, xf[0], acc[0][nt]);
          acc[1][nt] = MFMA16(wf, xf[1], acc[1][nt]);
        } else {  // Q/K: D = X * W^T -> out[row][n]
          acc[0][nt] = MFMA16(xf[0], wf, acc[0][nt]);
          acc[1][nt] = MFMA16(xf[1], wf, acc[1][nt]);
        }
      }
    }
  }

  if (proj != 2) {
    // fragment-major: idx = (R>>4)*4096 + (h>>5)*512 + ((h>>3)&3)*128
    //                       + (R&15)*8 + (h&7)
    const float cs = (proj == 0) ? 0.090168440f : 1.0f;  // log2(e)/16
    __bf16* __restrict__ O = (proj == 0) ? QF : KF;
#pragma unroll
    for (int rt = 0; rt < 2; ++rt)
#pragma unroll
      for (int nt = 0; nt < 16; ++nt) {
        int h = nt * 16 + lo;
        float bb = bias[h];
        size_t hpart = (size_t)((h >> 5) << 9) + (((h >> 3) & 3) << 7) + (h & 7);
#pragma unroll
        for (int r = 0; r < 4; ++r) {
          int R = r0 + rt * 16 + g * 4 + r;  // C-layout row
          O[((size_t)(R >> 4) << 12) + hpart + ((R & 15) << 3)] =
              (__bf16)((acc[rt][nt][r] + bb) * cs);
        }
      }
  } else {
    // V fragment-major: idx = (n>>6)*16384 + (h>>4)*1024 + ((n>>3)&7)*128
    //                         + (h&15)*8 + (n&7)
    const int bidx = r0 >> 11;
    const int nb = r0 & 2047;
    __bf16* __restrict__ Vo = VF + (size_t)bidx * 524288;
#pragma unroll
    for (int rt = 0; rt < 2; ++rt)
#pragma unroll
      for (int ht = 0; ht < 16; ++ht)
#pragma unroll
        for (int r = 0; r < 4; ++r) {
          int h = ht * 16 + g * 4 + r;       // C-layout row = h
          int n = nb + rt * 16 + lo;         // C-layout col = kv
          Vo[((size_t)(n >> 6) << 14) + ((h >> 4) << 10) + (((n >> 3) & 7) << 7) +
             ((h & 15) << 3) + (n & 7)] = (__bf16)(acc[rt][ht][r] + bias[h]);
        }
  }
}

// ---------------------------------------------------------------------------
// Attention: grid = 8 b x 16 qt x S; 4 warps x 32 q-rows (QBLK=128).
// KVBLK=32: K/V tiles 16KB each, double-buffered (64KB) + P 4x2560B (10KB)
// = 75.8KB LDS -> TWO independent blocks per CU (8 waves/CU, barrier-
// decoupled). setprio(1) around MFMA clusters (T5).
// ---------------------------------------------------------------------------
__global__ __launch_bounds__(256, 2) void attn_kernel(
    const __bf16* __restrict__ QF, const __bf16* __restrict__ KF,
    const __bf16* __restrict__ VF, const float* __restrict__ mb,
    float* __restrict__ Opart, float* __restrict__ mpart,
    float* __restrict__ lpart, float* __restrict__ out,
    int chunk, int direct) {
  extern __shared__ char smem[];  // [K 2x16K][V 2x16K][P 4x2560]
  const int bid = blockIdx.x;
  const int b = bid & 7;            // batch -> XCD pinning
  const int rest = bid >> 3;
  const int qt = rest & 15;
  const int s = rest >> 4;
  const int tid = threadIdx.x;
  const int w = tid >> 6, l = tid & 63, lo = l & 15, g = l >> 4;
  const int q0 = qt * 128 + w * 32;
  const __bf16* __restrict__ Qb = QF + ((size_t)b * 2048 + q0) * 256;
  const __bf16* __restrict__ Kb = KF + (size_t)b * 2048 * 256;
  const __bf16* __restrict__ Vb = VF + (size_t)b * 524288;
  const float* __restrict__ mbb = mb + b * 2048;
  // P: per warp 2 u-tiles x 16 rows x stride 40 elems (80B, 16B-aligned)
  __bf16* Pw = (__bf16*)(smem + 65536) + w * 1280;

  bf16x8 qf[2][8];  // 2 q-row-tiles, B-operand frags
#pragma unroll
  for (int u = 0; u < 2; ++u)
#pragma unroll
    for (int hs = 0; hs < 8; ++hs)
      qf[u][hs] = *(const bf16x8*)&Qb[u * 4096 + hs * 512 + l * 8];

  f32x4 oacc[2][16];
#pragma unroll
  for (int u = 0; u < 2; ++u)
#pragma unroll
    for (int i = 0; i < 16; ++i) oacc[u][i] = (f32x4){0.f, 0.f, 0.f, 0.f};
  float m[2] = {-3.0e28f, -3.0e28f}, lsum[2] = {0.f, 0.f};

  const int kv0 = s * chunk;
  const int niter = chunk >> 5;

  // stage kv-32 tile into buffer: warp w does 4 K + 4 V gload16 (8KB/warp).
  // K: 16KB contiguous. V: 16 ht-chunks of 1KB (global ht stride 2KB,
  // +((kvb>>5)&1)*1KB for the kv-half), warp w covers ht = 4w..4w+3.
  #define STAGE(kvb, buf)                                                     \
    {                                                                         \
      const char* gk = (const char*)(Kb + (size_t)(kvb) * 256) + w * 4096 +   \
                       l * 16;                                                \
      char* lk = smem + (buf)*16384 + w * 4096;                               \
      gload16(gk, lk);                                                        \
      gload16(gk + 1024, lk + 1024);                                          \
      gload16(gk + 2048, lk + 2048);                                          \
      gload16(gk + 3072, lk + 3072);                                          \
      const char* gv = (const char*)(Vb + (((size_t)(kvb) >> 6) << 14) +      \
                                     (((kvb) >> 5) & 1) * 512) +              \
                       w * 8192 + l * 16;                                     \
      char* lv = smem + 32768 + (buf)*16384 + w * 4096;                       \
      gload16(gv, lv);                                                        \
      gload16(gv + 2048, lv + 1024);                                          \
      gload16(gv + 4096, lv + 2048);                                          \
      gload16(gv + 6144, lv + 3072);                                          \
    }

  STAGE(kv0, 0);
  __syncthreads();  // drains vmcnt -> tile 0 visible

  for (int it = 0; it < niter; ++it) {
    const int kvb = kv0 + (it << 5);
    const int cur = it & 1;
    if (it + 1 < niter) STAGE(kvb + 32, cur ^ 1);  // prefetch into other buf
    const char* kbase = smem + cur * 16384;
    const char* vbase = smem + 32768 + cur * 16384;

    // QK^T: each K frag feeds both q-tiles
    f32x4 sacc[2][2];
#pragma unroll
    for (int u = 0; u < 2; ++u)
#pragma unroll
      for (int t = 0; t < 2; ++t) sacc[u][t] = (f32x4){0.f, 0.f, 0.f, 0.f};
    __builtin_amdgcn_s_setprio(1);
#pragma unroll
    for (int t = 0; t < 2; ++t)
#pragma unroll
      for (int hs = 0; hs < 8; ++hs) {
        bf16x8 kf = *(const bf16x8*)(kbase + t * 8192 + hs * 1024 + l * 16);
        sacc[0][t] = MFMA16(kf, qf[0][hs], sacc[0][t]);
        sacc[1][t] = MFMA16(kf, qf[1][hs], sacc[1][t]);
      }
    __builtin_amdgcn_s_setprio(0);

    // mask bias (shared across q-tiles) + per-tile online softmax
    f32x4 bias4[2];
#pragma unroll
    for (int t = 0; t < 2; ++t)
      bias4[t] = *(const f32x4*)&mbb[kvb + t * 16 + g * 4];
#pragma unroll
    for (int u = 0; u < 2; ++u) {
      float tmax = -3.4e38f;
#pragma unroll
      for (int t = 0; t < 2; ++t)
#pragma unroll
        for (int r = 0; r < 4; ++r) {
          sacc[u][t][r] += bias4[t][r];
          tmax = fmaxf(tmax, sacc[u][t][r]);
        }
      tmax = fmaxf(tmax, __shfl_xor(tmax, 16));
      tmax = fmaxf(tmax, __shfl_xor(tmax, 32));
      if (!__all(tmax <= m[u] + 8.0f)) {  // defer-max rescale
        float mn = fmaxf(m[u], tmax);
        float f = EXP2(m[u] - mn);
        lsum[u] *= f;
#pragma unroll
        for (int i = 0; i < 16; ++i) {
          oacc[u][i][0] *= f; oacc[u][i][1] *= f;
          oacc[u][i][2] *= f; oacc[u][i][3] *= f;
        }
        m[u] = mn;
      }
#pragma unroll
      for (int t = 0; t < 2; ++t) {
        float p0 = EXP2(sacc[u][t][0] - m[u]);
        float p1 = EXP2(sacc[u][t][1] - m[u]);
        float p2 = EXP2(sacc[u][t][2] - m[u]);
        float p3 = EXP2(sacc[u][t][3] - m[u]);
        lsum[u] += (p0 + p1) + (p2 + p3);
        bf16x4 pk;
        pk[0] = (__bf16)p0; pk[1] = (__bf16)p1;
        pk[2] = (__bf16)p2; pk[3] = (__bf16)p3;
        *(bf16x4*)&Pw[u * 640 + lo * 40 + t * 16 + g * 4] = pk;
      }
    }
    // P frags (same-wave LDS write->read), one kv-32 frag per q-tile
    bf16x8 pf[2];
#pragma unroll
    for (int u = 0; u < 2; ++u)
      pf[u] = *(const bf16x8*)&Pw[u * 640 + lo * 40 + g * 8];
    // PV: each V frag feeds both q-tiles
    __builtin_amdgcn_s_setprio(1);
#pragma unroll
    for (int ht = 0; ht < 16; ++ht) {
      bf16x8 vf = *(const bf16x8*)(vbase + ht * 1024 + l * 16);
      oacc[0][ht] = MFMA16(vf, pf[0], oacc[0][ht]);
      oacc[1][ht] = MFMA16(vf, pf[1], oacc[1][ht]);
    }
    __builtin_amdgcn_s_setprio(0);
    __syncthreads();  // drains vmcnt (prefetch landed); LDS reads done
  }

#pragma unroll
  for (int u = 0; u < 2; ++u) {
    float ls = lsum[u];
    ls += __shfl_xor(ls, 16);
    ls += __shfl_xor(ls, 32);
    const int q0u = q0 + u * 16;
    if (direct) {
      float inv = 1.0f / ls;
      float* __restrict__ Ob = out + ((size_t)b * 2048 + q0u) * 256;
#pragma unroll
      for (int ht = 0; ht < 16; ++ht) {
        f32x4 v = oacc[u][ht];
        v[0] *= inv; v[1] *= inv; v[2] *= inv; v[3] *= inv;
        *(f32x4*)&Ob[lo * 256 + ht * 16 + g * 4] = v;
      }
    } else {
      const size_t rowbase = (size_t)(s * 8 + b) * 2048 + q0u;
      float* __restrict__ Ob = Opart + rowbase * 256;
#pragma unroll
      for (int ht = 0; ht < 16; ++ht)
        *(f32x4*)&Ob[lo * 256 + ht * 16 + g * 4] = oacc[u][ht];
      if (l < 16) {
        mpart[rowbase + lo] = m[u];
        lpart[rowbase + lo] = ls;
      }
    }
  }
}

// ---------------------------------------------------------------------------
// Combine: out[row][h] = sum_s 2^(m_s-M) O_s[row][h] / sum_s 2^(m_s-M) l_s
// ---------------------------------------------------------------------------
__global__ __launch_bounds__(256) void combine_kernel(
    const float* __restrict__ Opart, const float* __restrict__ mpart,
    const float* __restrict__ lpart, float* __restrict__ out, int nsplit) {
  int t = blockIdx.x * 256 + threadIdx.x;
  int row = t >> 6;
  int h4 = (t & 63) << 2;
  float M = -3.4e38f;
  for (int s = 0; s < nsplit; ++s) M = fmaxf(M, mpart[s * 16384 + row]);
  f32x4 acc = (f32x4){0.f, 0.f, 0.f, 0.f};
  float denom = 0.f;
  for (int s = 0; s < nsplit; ++s) {
    float wgt = EXP2(mpart[s * 16384 + row] - M);
    denom += wgt * lpart[s * 16384 + row];
    f32x4 o = *(const f32x4*)&Opart[((size_t)s * 16384 + row) * 256 + h4];
    acc[0] += wgt * o[0]; acc[1] += wgt * o[1];
    acc[2] += wgt * o[2]; acc[3] += wgt * o[3];
  }
  float inv = 1.0f / denom;
  f32x4 r;
  r[0] = acc[0] * inv; r[1] = acc[1] * inv;
  r[2] = acc[2] * inv; r[3] = acc[3] * inv;
  *(f32x4*)&out[(size_t)row * 256 + h4] = r;
}

// ---------------------------------------------------------------------------
extern "C" void kernel_launch(void* const* d_in, const int* in_sizes, int n_in,
                              void* d_out, int out_size, void* d_ws, size_t ws_size,
                              hipStream_t stream) {
  const float* A = (const float*)d_in[0];
  const float* B = (const float*)d_in[1];
  const int* mask = (const int*)d_in[2];
  const float* Wq = (const float*)d_in[3];
  const float* bq = (const float*)d_in[4];
  const float* Wk = (const float*)d_in[5];
  const float* bk = (const float*)d_in[6];
  const float* Wv = (const float*)d_in[7];
  const float* bv = (const float*)d_in[8];

  char* ws = (char*)d_ws;
  __bf16* QF = (__bf16*)(ws);                         // 8 MB
  __bf16* KF = (__bf16*)(ws + (8ull << 20));          // 8 MB
  __bf16* VF = (__bf16*)(ws + (16ull << 20));         // 8 MB
  float* mb = (float*)(ws + (24ull << 20));           // 64 KB
  float* mpart = (float*)(ws + (24ull << 20) + 0x10000);   // <=256 KB
  float* lpart = (float*)(ws + (24ull << 20) + 0x60000);   // <=256 KB
  float* Opart = (float*)(ws + (25ull << 20));             // S * 16 MB

  const size_t base = 25ull << 20;
  const size_t part = 16ull << 20;
  int S;
  if (ws_size >= base + 4 * part) S = 4;
  else if (ws_size >= base + 2 * part) S = 2;
  else if (ws_size >= base + 1 * part) S = 1;
  else S = 0;  // direct mode (no split)

  const int SMEM = 65536 + 4 * 1280 * 2;  // 75776 B -> 2 blocks/CU
  (void)hipFuncSetAttribute((const void*)attn_kernel,
                            hipFuncAttributeMaxDynamicSharedMemorySize, SMEM);

  mask_kernel<<<64, 256, 0, stream>>>(mask, mb);
  proj_kernel<<<384, 256, 0, stream>>>(A, B, Wq, bq, Wk, bk, Wv, bv, QF, KF, VF);
  if (S == 0) {
    attn_kernel<<<128, 256, SMEM, stream>>>(QF, KF, VF, mb, nullptr, nullptr,
                                            nullptr, (float*)d_out, 2048, 1);
  } else {
    attn_kernel<<<128 * S, 256, SMEM, stream>>>(QF, KF, VF, mb, Opart, mpart,
                                                lpart, nullptr, 2048 / S, 0);
    combine_kernel<<<4096, 256, 0, stream>>>(Opart, mpart, lpart,
                                             (float*)d_out, S);
  }
}